// Round 12
// baseline (321.410 us; speedup 1.0000x reference)
//
#include <hip/hip_runtime.h>
#include <hip/hip_bf16.h>

typedef int int32x4 __attribute__((ext_vector_type(4)));
typedef signed char i8;

#define B_ 2
#define S_ 1024
#define E_ 4096
#define H_ 16
#define D_ 256

#define MFMA_I8(a, b, c) __builtin_amdgcn_mfma_i32_16x16x64_i8((a), (b), (c), 0, 0, 0)

__device__ __forceinline__ int32x4 ld16(const void* p) {
    return *reinterpret_cast<const int32x4*>(p);
}

// async global->LDS, 16B per lane. LDS dest = wave-uniform base + lane*16.
__device__ __forceinline__ void gload16(const void* g, void* l) {
    __builtin_amdgcn_global_load_lds(
        (const __attribute__((address_space(1))) void*)g,
        (__attribute__((address_space(3))) void*)l, 16, 0, 0);
}

#define WAIT_VM1()  asm volatile("s_waitcnt vmcnt(1)" ::: "memory")
#define WAIT_VM0()  asm volatile("s_waitcnt vmcnt(0)" ::: "memory")
#define COMPILER_FENCE() asm volatile("" ::: "memory")

// ---------------- packed-A layout ----------------
// Xp[mb][kb][ch*16+rr][16] : mb=row/16, rr=row%16, kb=col/64, ch=(col%64)/16.
// A fragment (mb, k-tile t) = 1KB at Xp + (mb*64+t)*1024, lane l reads +l*16
// => per-instruction fully coalesced (lanes contiguous 1KB).

// fp32 (integer-valued) -> int8 PACKED (for X / GEMM-A operands)
__global__ void k_f32_to_i8_packed(const float* __restrict__ src, i8* __restrict__ dst, int n4) {
    int i = blockIdx.x * blockDim.x + threadIdx.x;
    if (i >= n4) return;
    float4 f = reinterpret_cast<const float4*>(src)[i];
    union { int w; i8 b[4]; } u;
    u.b[0] = (i8)f.x; u.b[1] = (i8)f.y; u.b[2] = (i8)f.z; u.b[3] = (i8)f.w;
    int r = i >> 10;              // row (E=4096 -> 1024 float4 per row)
    int c = (i & 1023) * 4;       // col
    int mb = r >> 4, rr = r & 15;
    int kb = c >> 6, ch = (c >> 4) & 3, bo4 = (c >> 2) & 3;
    int didx = ((mb * 64 + kb) * 64 + ch * 16 + rr) * 4 + bo4;
    reinterpret_cast<int*>(dst)[didx] = u.w;
}

// 4 weight matrices in one launch, plain row-major (B operands stay LDS-staged)
__global__ void k_w_to_i8(const float* __restrict__ w0, const float* __restrict__ w1,
                          const float* __restrict__ w2, const float* __restrict__ w3,
                          i8* __restrict__ d0, i8* __restrict__ d1,
                          i8* __restrict__ d2, i8* __restrict__ d3, int n4) {
    int i = blockIdx.x * blockDim.x + threadIdx.x;
    if (i >= n4) return;
    const float* src = (blockIdx.y == 0) ? w0 : (blockIdx.y == 1) ? w1 : (blockIdx.y == 2) ? w2 : w3;
    i8* dst = (blockIdx.y == 0) ? d0 : (blockIdx.y == 1) ? d1 : (blockIdx.y == 2) ? d2 : d3;
    float4 f = reinterpret_cast<const float4*>(src)[i];
    union { int w; i8 b[4]; } u;
    u.b[0] = (i8)f.x; u.b[1] = (i8)f.y; u.b[2] = (i8)f.z; u.b[3] = (i8)f.w;
    reinterpret_cast<int*>(dst)[i] = u.w;
}

// ---------------- sin/cos table [S][32] ----------------
__global__ void k_sincos(float* __restrict__ sin_t, float* __restrict__ cos_t) {
    int idx = blockIdx.x * blockDim.x + threadIdx.x;
    if (idx >= S_ * 32) return;
    int s = idx >> 5, i = idx & 31;
    float ex = (float)(2 * i) / 64.0f;
    float invf = 1.0f / powf(10000.0f, ex);
    float arg = (float)s * invf;
    sin_t[idx] = (float)sin((double)arg);
    cos_t[idx] = (float)cos((double)arg);
}

// ---------------- int8 GEMM core ----------------
// Xp: PACKED A (fragment-linear). W: [N][K] i8 row-major.
// BM=256, BN=128, BK=64, 8 waves (4M x 2N), per-wave 64x64 output.
// A: coalesced global->VGPR fragment loads (1KB/instr), double-buffered regs.
// B: LDS-staged via global_load_lds, triple-buffered 3x8KB=24KB, XOR swizzle.
// Block mapping: n-FASTEST within each XCD chunk -> each XCD owns ONE A
// m-panel (1MB, fits its private 4MB L2; previous m-fastest mapping spread
// all 8 m-panels = 8.4MB over each XCD's L2 -> thrash to L3, the R10 miss).
// W loses within-XCD reuse but is the small flow (16KB/CU/tile vs A 64KB);
// its 8-way cross-XCD reuse is served by L3.
template<bool OUT_I8>
__device__ __forceinline__ void gemm_core(
    const i8* __restrict__ Xp, const i8* __restrict__ W, const float* __restrict__ bias,
    void* __restrict__ out, float alpha, int M, int N, int K, i8* lds)
{
    const int nt = K >> 6;                      // K-tiles of 64 bytes
    // bijective XCD swizzle (nwg % 8 == 0)
    const int nwg = (M >> 8) * (N >> 7);
    const int q = nwg >> 3;
    const int lin = blockIdx.x;
    const int wg = (lin & 7) * q + (lin >> 3);
    // n-fastest decode: XCD chunk [x*q, (x+1)*q) covers m = x*q/nbn .. few,
    // all n. For M=2048,N=4096: q=32, nbn=32 -> exactly one m-panel per XCD.
    const int nbn = N >> 7;
    const int m0 = (wg / nbn) * 256, n0 = (wg % nbn) * 128;

    const int tid = threadIdx.x, lane = tid & 63, wave = tid >> 6;
    const int wr = wave >> 1, wc = wave & 1, l4 = lane & 15, lh = lane >> 4;

    // B ds_read offsets (swizzled): granule g' = lh ^ ((l4>>1)&3)
    const int g4 = lh ^ ((l4 >> 1) & 3);
    const int boff = (wc * 64 + l4) * 64 + g4 * 16;   // within 8KB buffer (+n*1024)

    // B stage source (pre-swizzled): 512 threads stage 128 rows x 64B;
    // row = tid>>2, granule (tid&3) ^ ((row>>1)&3)
    const int srow = tid >> 2;
    const int sg = (tid & 3) ^ ((tid >> 3) & 3);
    const i8* Bsrc = W + (size_t)(n0 + srow) * K + sg * 16;
    const int ldst = wave * 1024;               // wave-uniform LDS base

    // A packed fragment base: mb = m0/16 + wr*4 + m, frag addr = (mb*64+t)*1024
    const i8* Ab = Xp + ((size_t)(m0 >> 4) + wr * 4) * 65536 + lane * 16;

#define STAGE_B(t_) gload16(Bsrc + (t_) * 64, lds + ((t_) % 3) * 8192 + ldst)

    int32x4 acc[4][4];
#pragma unroll
    for (int m = 0; m < 4; ++m)
#pragma unroll
        for (int n = 0; n < 4; ++n) acc[m][n] = int32x4{0, 0, 0, 0};

    int32x4 aR0[4], aR1[4];

    // prologue: A(0) -> aR0 (4 coalesced loads), then B(0), B(1) gloads.
    // vmem queue (oldest first): A0 x4, B0, B1.
#pragma unroll
    for (int m = 0; m < 4; ++m) aR0[m] = ld16(Ab + m * 65536);
    STAGE_B(0);
    STAGE_B(1);

#define TILE_BODY(t_, AC, AN) do {                                            \
        if ((t_) + 1 < nt) { WAIT_VM1(); } else { WAIT_VM0(); }               \
        __builtin_amdgcn_s_barrier();                                         \
        COMPILER_FENCE();                                                     \
        if ((t_) + 1 < nt) {                                                  \
            AN[0] = ld16(Ab + ((t_) + 1) * 1024);                             \
            AN[1] = ld16(Ab + 65536 + ((t_) + 1) * 1024);                     \
            AN[2] = ld16(Ab + 131072 + ((t_) + 1) * 1024);                    \
            AN[3] = ld16(Ab + 196608 + ((t_) + 1) * 1024);                    \
        }                                                                     \
        if ((t_) + 2 < nt) STAGE_B((t_) + 2);                                 \
        {                                                                     \
            const i8* Tb_ = lds + ((t_) % 3) * 8192;                          \
            int32x4 b0 = ld16(Tb_ + boff);        int32x4 b1 = ld16(Tb_ + boff + 1024); \
            int32x4 b2 = ld16(Tb_ + boff + 2048); int32x4 b3 = ld16(Tb_ + boff + 3072); \
            __builtin_amdgcn_s_setprio(1);                                    \
            acc[0][0] = MFMA_I8(AC[0], b0, acc[0][0]);                        \
            acc[0][1] = MFMA_I8(AC[0], b1, acc[0][1]);                        \
            acc[0][2] = MFMA_I8(AC[0], b2, acc[0][2]);                        \
            acc[0][3] = MFMA_I8(AC[0], b3, acc[0][3]);                        \
            acc[1][0] = MFMA_I8(AC[1], b0, acc[1][0]);                        \
            acc[1][1] = MFMA_I8(AC[1], b1, acc[1][1]);                        \
            acc[1][2] = MFMA_I8(AC[1], b2, acc[1][2]);                        \
            acc[1][3] = MFMA_I8(AC[1], b3, acc[1][3]);                        \
            acc[2][0] = MFMA_I8(AC[2], b0, acc[2][0]);                        \
            acc[2][1] = MFMA_I8(AC[2], b1, acc[2][1]);                        \
            acc[2][2] = MFMA_I8(AC[2], b2, acc[2][2]);                        \
            acc[2][3] = MFMA_I8(AC[2], b3, acc[2][3]);                        \
            acc[3][0] = MFMA_I8(AC[3], b0, acc[3][0]);                        \
            acc[3][1] = MFMA_I8(AC[3], b1, acc[3][1]);                        \
            acc[3][2] = MFMA_I8(AC[3], b2, acc[3][2]);                        \
            acc[3][3] = MFMA_I8(AC[3], b3, acc[3][3]);                        \
            __builtin_amdgcn_s_setprio(0);                                    \
        }                                                                     \
    } while (0)

    for (int tt = 0; tt < nt; tt += 2) {
        TILE_BODY(tt, aR0, aR1);
        TILE_BODY(tt + 1, aR1, aR0);
    }
#undef TILE_BODY
#undef STAGE_B

#pragma unroll
    for (int m = 0; m < 4; ++m)
#pragma unroll
        for (int n = 0; n < 4; ++n)
#pragma unroll
            for (int r = 0; r < 4; ++r) {
                int grow = m0 + wr * 64 + m * 16 + lh * 4 + r;
                int gcol = n0 + wc * 64 + n * 16 + l4;
                float y = alpha * (float)acc[m][n][r] + bias[gcol];
                if (OUT_I8) {
                    float v = rintf(y);
                    v = fminf(fmaxf(v, -128.0f), 127.0f);
                    reinterpret_cast<i8*>(out)[(size_t)grow * N + gcol] = (i8)v;
                } else {
                    reinterpret_cast<float*>(out)[(size_t)grow * N + gcol] = y;
                }
            }
}

// fused Q/K/V projection: blockIdx.z selects weight/bias/dst
__global__ __launch_bounds__(512, 4) void k_gemm_qkv(
    const i8* __restrict__ Xp,
    const i8* __restrict__ w0, const i8* __restrict__ w1, const i8* __restrict__ w2,
    const float* __restrict__ b0, const float* __restrict__ b1, const float* __restrict__ b2,
    i8* __restrict__ o0, i8* __restrict__ o1, i8* __restrict__ o2,
    float alpha, int M, int N, int K)
{
    __shared__ __align__(16) i8 lds[3 * 8192];
    int z = blockIdx.z;
    const i8* W = (z == 0) ? w0 : (z == 1) ? w1 : w2;
    const float* bias = (z == 0) ? b0 : (z == 1) ? b1 : b2;
    i8* out = (z == 0) ? o0 : (z == 1) ? o1 : o2;
    gemm_core<true>(Xp, W, bias, out, alpha, M, N, K, lds);
}

__global__ __launch_bounds__(512, 4) void k_gemm_out(
    const i8* __restrict__ Xp, const i8* __restrict__ W, const float* __restrict__ bias,
    float* __restrict__ out, float alpha, int M, int N, int K)
{
    __shared__ __align__(16) i8 lds[3 * 8192];
    gemm_core<false>(Xp, W, bias, out, alpha, M, N, K, lds);
}

// ---------------- rope: (B,S,H,D) i8 -> (B,H,S,D) i8, rotary on d<64 ----------------
__global__ void k_rope(const i8* __restrict__ qin, const i8* __restrict__ kin,
                       i8* __restrict__ qout, i8* __restrict__ kout,
                       const float* __restrict__ sin_t, const float* __restrict__ cos_t)
{
    const i8* in = blockIdx.y ? kin : qin;
    i8* outp = blockIdx.y ? kout : qout;
    int row = blockIdx.x * 2 + (threadIdx.x >> 7);   // (b*S + s)*H + h
    int i = threadIdx.x & 127;
    int b = row / (S_ * H_);
    int s = (row / H_) % S_;
    int h = row % H_;
    const i8* src = in + (size_t)row * D_ + i * 2;
    i8 x1 = src[0], x2 = src[1];
    i8 o1, o2;
    if (i < 32) {
        float c = cos_t[s * 32 + i], sn = sin_t[s * 32 + i];
        float f1 = (float)x1, f2 = (float)x2;
        float r0 = __fadd_rn(__fmul_rn(f1, c), __fmul_rn(-f2, sn));
        float r1 = __fadd_rn(__fmul_rn(f2, c), __fmul_rn(f1, sn));
        r0 = truncf(fminf(fmaxf(r0, -128.0f), 127.0f));
        r1 = truncf(fminf(fmaxf(r1, -128.0f), 127.0f));
        o1 = (i8)r0; o2 = (i8)r1;
    } else { o1 = x1; o2 = x2; }
    size_t ob = ((size_t)(b * H_ + h) * S_ + s) * D_ + i * 2;
    outp[ob] = o1; outp[ob + 1] = o2;
}

// ---------------- V transpose: (B,S,H,D) -> (B,H,D,S) ----------------
__global__ void k_vtrans(const i8* __restrict__ vin, i8* __restrict__ vout) {
    __shared__ int tile[64][17];
    int bh = blockIdx.z;
    int b = bh >> 4, h = bh & 15;
    int s0 = blockIdx.x * 64, d0 = blockIdx.y * 64;
    int t = threadIdx.x;
    {
        int sr = t >> 2, dq = (t & 3) * 16;
        int32x4 v = ld16(vin + ((size_t)(b * S_ + s0 + sr) * H_ + h) * D_ + d0 + dq);
#pragma unroll
        for (int j = 0; j < 4; ++j) tile[sr][dq / 4 + j] = v[j];
    }
    __syncthreads();
    {
        int dr = t >> 2, sq = (t & 3) * 16;
        union { int32x4 v; i8 b[16]; } u;
        const i8* tb = reinterpret_cast<const i8*>(tile);
#pragma unroll
        for (int j = 0; j < 16; ++j) u.b[j] = tb[(sq + j) * 68 + dr];
        *reinterpret_cast<int32x4*>(vout + ((size_t)bh * D_ + d0 + dr) * S_ + s0 + sq) = u.v;
    }
}

// ---------------- fused int8 attention ----------------
// Q,K: (B,H,S,D) post-rope. V: (B,H,D,S). O: PACKED (GEMM-A layout).
struct AttnShared {
    float slx[4][32];
    float r127[32];
    __align__(16) i8 plds[32][80];
};

__device__ __forceinline__ void attn_chunk(int qc, int bh, int tid,
    const i8* __restrict__ Qh, const i8* __restrict__ Kb, const i8* __restrict__ Vb,
    i8* __restrict__ Opk, AttnShared& sh)
{
    const float C2 = 1.25e-5f * 1.44269504088896f;   // A_QK/16 * log2(e)
    const float APV = 1.0f / 127.0f;
    const int lane = tid & 63, wave = tid >> 6;
    const int l4 = lane & 15, lh = lane >> 4;
    const i8* Qb = Qh + (size_t)(qc * 32) * D_;
    const int nt = (qc * 32 + 31) / 64 + 1;

    int32x4 aq[2][4];
#pragma unroll
    for (int m = 0; m < 2; ++m)
#pragma unroll
        for (int kk = 0; kk < 4; ++kk)
            aq[m][kk] = ld16(Qb + (size_t)(m * 16 + l4) * D_ + kk * 64 + lh * 16);

    float sum_[2][4];
#pragma unroll
    for (int m = 0; m < 2; ++m)
#pragma unroll
        for (int r = 0; r < 4; ++r) sum_[m][r] = 0.0f;

    for (int kt = 0; kt < nt; ++kt) {
        int cb = kt * 64 + wave * 16;
        int32x4 acc0 = int32x4{0,0,0,0}, acc1 = int32x4{0,0,0,0};
#pragma unroll
        for (int kk = 0; kk < 4; ++kk) {
            int32x4 bf = ld16(Kb + (size_t)(cb + l4) * D_ + kk * 64 + lh * 16);
            acc0 = MFMA_I8(aq[0][kk], bf, acc0);
            acc1 = MFMA_I8(aq[1][kk], bf, acc1);
        }
        int gcol = cb + l4;
#pragma unroll
        for (int m = 0; m < 2; ++m) {
            int32x4 accm = m ? acc1 : acc0;
#pragma unroll
            for (int r = 0; r < 4; ++r) {
                int grow = qc * 32 + m * 16 + lh * 4 + r;
                float e = (gcol <= grow) ? exp2f((float)accm[r] * C2) : 0.0f;
                sum_[m][r] += e;
            }
        }
    }

#pragma unroll
    for (int m = 0; m < 2; ++m)
#pragma unroll
        for (int r = 0; r < 4; ++r) {
            float s = sum_[m][r];
            s += __shfl_xor(s, 1);
            s += __shfl_xor(s, 2);
            s += __shfl_xor(s, 4);
            s += __shfl_xor(s, 8);
            if (l4 == 0) sh.slx[wave][m * 16 + lh * 4 + r] = s;
        }
    __syncthreads();
    if (tid < 32)
        sh.r127[tid] = 127.0f /
            (sh.slx[0][tid] + sh.slx[1][tid] + sh.slx[2][tid] + sh.slx[3][tid]);
    __syncthreads();

    int32x4 oacc[2][4];
#pragma unroll
    for (int m = 0; m < 2; ++m)
#pragma unroll
        for (int n = 0; n < 4; ++n) oacc[m][n] = int32x4{0, 0, 0, 0};

    for (int kt = 0; kt < nt; ++kt) {
        int cb = kt * 64 + wave * 16;
        int32x4 acc0 = int32x4{0,0,0,0}, acc1 = int32x4{0,0,0,0};
#pragma unroll
        for (int kk = 0; kk < 4; ++kk) {
            int32x4 bf = ld16(Kb + (size_t)(cb + l4) * D_ + kk * 64 + lh * 16);
            acc0 = MFMA_I8(aq[0][kk], bf, acc0);
            acc1 = MFMA_I8(aq[1][kk], bf, acc1);
        }
        int gcol = cb + l4;
        i8 pv[2][4];
#pragma unroll
        for (int m = 0; m < 2; ++m) {
            int32x4 accm = m ? acc1 : acc0;
#pragma unroll
            for (int r = 0; r < 4; ++r) {
                int rowi = m * 16 + lh * 4 + r;
                int grow = qc * 32 + rowi;
                float e = (gcol <= grow) ? exp2f((float)accm[r] * C2) : 0.0f;
                pv[m][r] = (i8)(int)rintf(e * sh.r127[rowi]);
            }
        }
        __syncthreads();
#pragma unroll
        for (int m = 0; m < 2; ++m)
#pragma unroll
            for (int r = 0; r < 4; ++r)
                sh.plds[m * 16 + lh * 4 + r][wave * 16 + l4] = pv[m][r];
        __syncthreads();
        int32x4 a0 = ld16(&sh.plds[l4][lh * 16]);
        int32x4 a1 = ld16(&sh.plds[16 + l4][lh * 16]);
#pragma unroll
        for (int n = 0; n < 4; ++n) {
            int32x4 bf = ld16(Vb + (size_t)(wave * 64 + n * 16 + l4) * S_ + kt * 64 + lh * 16);
            oacc[0][n] = MFMA_I8(a0, bf, oacc[0][n]);
            oacc[1][n] = MFMA_I8(a1, bf, oacc[1][n]);
        }
    }

    // epilogue -> PACKED o8 (GEMM-A fragment-linear layout)
    int b = bh >> 4, h = bh & 15;
#pragma unroll
    for (int m = 0; m < 2; ++m) {
        size_t mbase = ((size_t)(b * 64 + qc * 2 + m) * 64 + (h * 4 + wave)) * 1024;
#pragma unroll
        for (int r = 0; r < 4; ++r)
#pragma unroll
            for (int n = 0; n < 4; ++n) {
                float o = rintf(APV * (float)oacc[m][n][r]);
                o = fminf(fmaxf(o, -128.0f), 127.0f);
                Opk[mbase + (size_t)(n * 16 + lh * 4 + r) * 16 + l4] = (i8)o;
            }
    }
}

// Pair chunks (p, 31-p): every block does ~17 k-tiles -> uniform runtime.
__global__ __launch_bounds__(256) void k_attn(const i8* __restrict__ Q, const i8* __restrict__ K,
                                              const i8* __restrict__ V, i8* __restrict__ O)
{
    __shared__ AttnShared sh;
    int bh = blockIdx.x;
    int p = blockIdx.y;
    int tid = threadIdx.x;
    const i8* Qh = Q + (size_t)bh * S_ * D_;
    const i8* Kb = K + (size_t)bh * S_ * D_;
    const i8* Vb = V + (size_t)bh * D_ * S_;
    attn_chunk((S_ / 32 - 1) - p, bh, tid, Qh, Kb, Vb, O, sh);
    attn_chunk(p, bh, tid, Qh, Kb, Vb, O, sh);
}

extern "C" void kernel_launch(void* const* d_in, const int* in_sizes, int n_in,
                              void* d_out, int out_size, void* d_ws, size_t ws_size,
                              hipStream_t stream) {
    const float* hs = (const float*)d_in[0];
    const float* Wq = (const float*)d_in[1];
    const float* Wk = (const float*)d_in[2];
    const float* Wv = (const float*)d_in[3];
    const float* Wo = (const float*)d_in[4];
    const float* bq = (const float*)d_in[5];
    const float* bk = (const float*)d_in[6];
    const float* bv = (const float*)d_in[7];
    const float* bo = (const float*)d_in[8];
    float* out = (float*)d_out;

    size_t off = 0;
    char* wsb = (char*)d_ws;
    auto carve = [&](size_t bytes) { char* p = wsb + off; off += (bytes + 255) & ~(size_t)255; return p; };
    const size_t ME = (size_t)B_ * S_ * E_;   // 8.4 MB
    const size_t EE = (size_t)E_ * E_;        // 16.8 MB
    i8* x8  = (i8*)carve(ME);    // PACKED
    i8* wq8 = (i8*)carve(EE);
    i8* wk8 = (i8*)carve(EE);
    i8* wv8 = (i8*)carve(EE);
    i8* wo8 = (i8*)carve(EE);
    i8* q8  = (i8*)carve(ME);
    i8* k8  = (i8*)carve(ME);
    i8* v8  = (i8*)carve(ME);
    i8* qr  = (i8*)carve(ME);
    i8* kr  = (i8*)carve(ME);
    i8* vt  = (i8*)carve(ME);
    i8* o8  = (i8*)carve(ME);    // PACKED
    float* sin_t = (float*)carve((size_t)S_ * 32 * 4);
    float* cos_t = (float*)carve((size_t)S_ * 32 * 4);

    int n4_me = (int)(ME / 4), n4_ee = (int)(EE / 4);
    k_f32_to_i8_packed<<<(n4_me + 255) / 256, 256, 0, stream>>>(hs, x8, n4_me);
    k_w_to_i8<<<dim3((n4_ee + 255) / 256, 4), 256, 0, stream>>>(
        Wq, Wk, Wv, Wo, wq8, wk8, wv8, wo8, n4_ee);
    k_sincos<<<(S_ * 32 + 255) / 256, 256, 0, stream>>>(sin_t, cos_t);

    const int M = B_ * S_, N = E_, Kd = E_;
    const int nwg = (M / 256) * (N / 128);   // 256-row x 128-col tiles
    k_gemm_qkv<<<dim3(nwg, 1, 3), 512, 0, stream>>>(
        x8, wq8, wk8, wv8, bq, bk, bv, q8, k8, v8, 0.00012f, M, N, Kd);

    k_rope<<<dim3((B_ * S_ * H_) / 2, 2), 256, 0, stream>>>(q8, k8, qr, kr, sin_t, cos_t);
    k_vtrans<<<dim3(S_ / 64, D_ / 64, B_ * H_), 256, 0, stream>>>(v8, vt);
    k_attn<<<dim3(B_ * H_, S_ / 64), 256, 0, stream>>>(qr, kr, vt, o8);

    k_gemm_out<<<nwg, 512, 0, stream>>>(o8, wo8, bo, out, 0.01f, M, N, Kd);
}

// Round 13
// 316.270 us; speedup vs baseline: 1.0163x; 1.0163x over previous
//
#include <hip/hip_runtime.h>
#include <hip/hip_bf16.h>

typedef int int32x4 __attribute__((ext_vector_type(4)));
typedef signed char i8;

#define B_ 2
#define S_ 1024
#define E_ 4096
#define H_ 16
#define D_ 256

#define MFMA_I8(a, b, c) __builtin_amdgcn_mfma_i32_16x16x64_i8((a), (b), (c), 0, 0, 0)

__device__ __forceinline__ int32x4 ld16(const void* p) {
    return *reinterpret_cast<const int32x4*>(p);
}

// async global->LDS, 16B per lane. LDS dest = wave-uniform base + lane*16.
__device__ __forceinline__ void gload16(const void* g, void* l) {
    __builtin_amdgcn_global_load_lds(
        (const __attribute__((address_space(1))) void*)g,
        (__attribute__((address_space(3))) void*)l, 16, 0, 0);
}

#define WAIT_VM3()  asm volatile("s_waitcnt vmcnt(3)" ::: "memory")
#define WAIT_VM1()  asm volatile("s_waitcnt vmcnt(1)" ::: "memory")
#define WAIT_VM0()  asm volatile("s_waitcnt vmcnt(0)" ::: "memory")
#define WAIT_LGKM0() do { asm volatile("s_waitcnt lgkmcnt(0)" ::: "memory"); \
                          __builtin_amdgcn_sched_barrier(0); } while (0)
#define COMPILER_FENCE() asm volatile("" ::: "memory")

// ---------------- fp32 (integer-valued) -> int8, coalesced ----------------
__device__ __forceinline__ int pack4(float4 f) {
    union { int w; i8 b[4]; } u;
    u.b[0] = (i8)f.x; u.b[1] = (i8)f.y; u.b[2] = (i8)f.z; u.b[3] = (i8)f.w;
    return u.w;
}

__global__ void k_f32_to_i8(const float* __restrict__ src, i8* __restrict__ dst, int n4) {
    int i = blockIdx.x * blockDim.x + threadIdx.x;
    if (i >= n4) return;
    reinterpret_cast<int*>(dst)[i] = pack4(reinterpret_cast<const float4*>(src)[i]);
}

// 4 weight matrices in one launch (blockIdx.y selects matrix)
__global__ void k_w_to_i8(const float* __restrict__ w0, const float* __restrict__ w1,
                          const float* __restrict__ w2, const float* __restrict__ w3,
                          i8* __restrict__ d0, i8* __restrict__ d1,
                          i8* __restrict__ d2, i8* __restrict__ d3, int n4) {
    int i = blockIdx.x * blockDim.x + threadIdx.x;
    if (i >= n4) return;
    const float* src = (blockIdx.y == 0) ? w0 : (blockIdx.y == 1) ? w1 : (blockIdx.y == 2) ? w2 : w3;
    i8* dst = (blockIdx.y == 0) ? d0 : (blockIdx.y == 1) ? d1 : (blockIdx.y == 2) ? d2 : d3;
    reinterpret_cast<int*>(dst)[i] = pack4(reinterpret_cast<const float4*>(src)[i]);
}

// ---------------- sin/cos table [S][32] ----------------
__global__ void k_sincos(float* __restrict__ sin_t, float* __restrict__ cos_t) {
    int idx = blockIdx.x * blockDim.x + threadIdx.x;
    if (idx >= S_ * 32) return;
    int s = idx >> 5, i = idx & 31;
    float ex = (float)(2 * i) / 64.0f;
    float invf = 1.0f / powf(10000.0f, ex);
    float arg = (float)s * invf;
    sin_t[idx] = (float)sin((double)arg);
    cos_t[idx] = (float)cos((double)arg);
}

// ============== R8 GEMM core (known-good; used by out-GEMM) ==============
// BM=256, BN=128, BK=64, 8 waves (4M x 2N), per-wave 64x64, triple-buffered
// 72KB LDS, counted vmcnt(3), XOR granule swizzle (0 conflicts verified).
template<bool OUT_I8>
__device__ __forceinline__ void gemm_core(
    const i8* __restrict__ X, const i8* __restrict__ W, const float* __restrict__ bias,
    void* __restrict__ out, float alpha, int M, int N, int K, i8* lds)
{
    const int nt = K >> 6;
    const int nwg = (M >> 8) * (N >> 7);
    const int q = nwg >> 3;
    const int lin = blockIdx.x;
    const int wg = (lin & 7) * q + (lin >> 3);
    const int nbm = M >> 8;
    const int m0 = (wg % nbm) * 256, n0 = (wg / nbm) * 128;

    const int tid = threadIdx.x, lane = tid & 63, wave = tid >> 6;
    const int wr = wave >> 1, wc = wave & 1, l4 = lane & 15, lh = lane >> 4;

    const int g4 = lh ^ ((l4 >> 1) & 3);
    const int aoff = (wr * 64 + l4) * 64 + g4 * 16;
    const int boff = 16384 + (wc * 64 + l4) * 64 + g4 * 16;

    const int srow = tid >> 2;
    const int sg = (tid & 3) ^ ((tid >> 3) & 3);
    const i8* Asrc = X + (size_t)(m0 + srow) * K + sg * 16;
    const i8* Bsrc = W + (size_t)(n0 + srow) * K + sg * 16;
    const size_t rstep = (size_t)128 * K;
    const int ldst = wave * 1024;

#define BUF3(t_) (lds + ((t_) % 3) * 24576)
#define STAGE3(t_) do { int kb_ = (t_) * 64; i8* lb_ = BUF3(t_);             \
        gload16(Asrc + kb_,         lb_ + ldst);                             \
        gload16(Asrc + rstep + kb_, lb_ + 8192 + ldst);                      \
        gload16(Bsrc + kb_,         lb_ + 16384 + ldst); } while (0)

    int32x4 acc[4][4];
#pragma unroll
    for (int m = 0; m < 4; ++m)
#pragma unroll
        for (int n = 0; n < 4; ++n) acc[m][n] = int32x4{0, 0, 0, 0};

    STAGE3(0);
    STAGE3(1);

    for (int t = 0; t < nt; ++t) {
        const i8* Tb = BUF3(t);
        if (t + 1 < nt) { WAIT_VM3(); } else { WAIT_VM0(); }
        __builtin_amdgcn_s_barrier();
        COMPILER_FENCE();

        if (t + 2 < nt) STAGE3(t + 2);

        int32x4 a0, a1, a2, a3, b0, b1, b2, b3;
        a0 = ld16(Tb + aoff);
        b0 = ld16(Tb + boff);        b1 = ld16(Tb + boff + 1024);
        b2 = ld16(Tb + boff + 2048); b3 = ld16(Tb + boff + 3072);
        a1 = ld16(Tb + aoff + 1024);
        a2 = ld16(Tb + aoff + 2048); a3 = ld16(Tb + aoff + 3072);
        __builtin_amdgcn_s_setprio(1);
        acc[0][0] = MFMA_I8(a0, b0, acc[0][0]);
        acc[0][1] = MFMA_I8(a0, b1, acc[0][1]);
        acc[0][2] = MFMA_I8(a0, b2, acc[0][2]);
        acc[0][3] = MFMA_I8(a0, b3, acc[0][3]);
        acc[1][0] = MFMA_I8(a1, b0, acc[1][0]);
        acc[1][1] = MFMA_I8(a1, b1, acc[1][1]);
        acc[1][2] = MFMA_I8(a1, b2, acc[1][2]);
        acc[1][3] = MFMA_I8(a1, b3, acc[1][3]);
        acc[2][0] = MFMA_I8(a2, b0, acc[2][0]);
        acc[2][1] = MFMA_I8(a2, b1, acc[2][1]);
        acc[2][2] = MFMA_I8(a2, b2, acc[2][2]);
        acc[2][3] = MFMA_I8(a2, b3, acc[2][3]);
        acc[3][0] = MFMA_I8(a3, b0, acc[3][0]);
        acc[3][1] = MFMA_I8(a3, b1, acc[3][1]);
        acc[3][2] = MFMA_I8(a3, b2, acc[3][2]);
        acc[3][3] = MFMA_I8(a3, b3, acc[3][3]);
        __builtin_amdgcn_s_setprio(0);
    }
#undef BUF3
#undef STAGE3

#pragma unroll
    for (int m = 0; m < 4; ++m)
#pragma unroll
        for (int n = 0; n < 4; ++n)
#pragma unroll
            for (int r = 0; r < 4; ++r) {
                int grow = m0 + wr * 64 + m * 16 + lh * 4 + r;
                int gcol = n0 + wc * 64 + n * 16 + l4;
                float y = alpha * (float)acc[m][n][r] + bias[gcol];
                if (OUT_I8) {
                    float v = rintf(y);
                    v = fminf(fmaxf(v, -128.0f), 127.0f);
                    reinterpret_cast<i8*>(out)[(size_t)grow * N + gcol] = (i8)v;
                } else {
                    reinterpret_cast<float*>(out)[(size_t)grow * N + gcol] = y;
                }
            }
}

// ============== 8-phase-template QKV GEMM (T3+T4 port, i8) ==============
// BM=256, BN=128, BK=64, 8 waves (4M x 2N), per-wave 64x64 (acc[4][4]).
// 2 LDS buffers x 24KB (A 16KB + B 8KB) = 48KB. Iter = 2 K-tiles, 4 phases:
//   P1(t0,m0-1): reads B[t0]x4 + A[t0]m0,1; stage SA(t1,h0)
//   P2(t0,m2-3): reads A m2,3; stage SA(t1,h1) + SB(t0+2); VMCNT(1)
//   P3(t1,m0-1): reads B[t1]x4 + A[t1]m0,1; stage SA(t0+2,h0)
//   P4(t1,m2-3): reads A m2,3; stage SA(t0+2,h1) + SB(t1+2); VMCNT(1)
// Each phase: reads -> stages -> [vmcnt] -> barrier -> lgkm(0)+sched_barrier
// -> setprio(1) 8 MFMA setprio(0) -> barrier.  vmcnt never 0 mid-loop.
// Buffer-release proof: B(t0) free after P1's trailing barrier (every wave's
// lgkm(0) precedes it); A(t0) after P2; B(t1) after P3; A(t1) after P4.
// Steady vmcnt queue at P2-end: [SB(t1), SA(t1,0), SA(t1,1), SB(t0+2)] ->
// vmcnt(1) drains first 3 (needed by P3/P4). P4-end symmetric.
__device__ __forceinline__ void gemm8p_core(
    const i8* __restrict__ X, const i8* __restrict__ W, const float* __restrict__ bias,
    i8* __restrict__ out, float alpha, int M, int N, int K, i8* lds)
{
    const int nt = K >> 6;
    const int nwg = (M >> 8) * (N >> 7);
    const int q = nwg >> 3;
    const int lin = blockIdx.x;
    const int wg = (lin & 7) * q + (lin >> 3);
    const int nbm = M >> 8;
    const int m0 = (wg % nbm) * 256, n0 = (wg / nbm) * 128;

    const int tid = threadIdx.x, lane = tid & 63, wave = tid >> 6;
    const int wr = wave >> 1, wc = wave & 1, l4 = lane & 15, lh = lane >> 4;

    const int g4 = lh ^ ((l4 >> 1) & 3);
    const int aoff = (wr * 64 + l4) * 64 + g4 * 16;            // A region (rows 0-255)
    const int boff = 16384 + (wc * 64 + l4) * 64 + g4 * 16;    // B region (rows 0-127)

    const int srow = tid >> 2;
    const int sg = (tid & 3) ^ ((tid >> 3) & 3);
    const i8* Asrc = X + (size_t)(m0 + srow) * K + sg * 16;    // + h*128*K + t*64
    const i8* Bsrc = W + (size_t)(n0 + srow) * K + sg * 16;    // + t*64
    const size_t hstep = (size_t)128 * K;
    const int ldst = wave * 1024;

#define BUF8(t_) (lds + ((t_) & 1) * 24576)
#define SA8(t_, h_) gload16(Asrc + (h_) * hstep + (t_) * 64, \
                            BUF8(t_) + (h_) * 8192 + ldst)
#define SB8(t_)     gload16(Bsrc + (t_) * 64, BUF8(t_) + 16384 + ldst)

    int32x4 acc[4][4];
#pragma unroll
    for (int m = 0; m < 4; ++m)
#pragma unroll
        for (int n = 0; n < 4; ++n) acc[m][n] = int32x4{0, 0, 0, 0};

    // prologue: buf0 fully staged+drained; SB(1) left in flight (steady shape)
    SA8(0, 0); SA8(0, 1); SB8(0);
    WAIT_VM0();
    SB8(1);
    __builtin_amdgcn_s_barrier();
    COMPILER_FENCE();

    for (int t0 = 0; t0 < nt; t0 += 2) {
        const int t1 = t0 + 1;
        const bool full = (t0 + 2 < nt);
        const i8* Tb0 = BUF8(t0);
        const i8* Tb1 = BUF8(t1);
        int32x4 a0, a1, b0, b1, b2, b3;

        // ---------- P1: t0, m0-1 ----------
        b0 = ld16(Tb0 + boff);        b1 = ld16(Tb0 + boff + 1024);
        b2 = ld16(Tb0 + boff + 2048); b3 = ld16(Tb0 + boff + 3072);
        a0 = ld16(Tb0 + aoff);        a1 = ld16(Tb0 + aoff + 1024);
        SA8(t1, 0);
        __builtin_amdgcn_s_barrier();
        WAIT_LGKM0();
        __builtin_amdgcn_s_setprio(1);
        acc[0][0] = MFMA_I8(a0, b0, acc[0][0]);
        acc[0][1] = MFMA_I8(a0, b1, acc[0][1]);
        acc[0][2] = MFMA_I8(a0, b2, acc[0][2]);
        acc[0][3] = MFMA_I8(a0, b3, acc[0][3]);
        acc[1][0] = MFMA_I8(a1, b0, acc[1][0]);
        acc[1][1] = MFMA_I8(a1, b1, acc[1][1]);
        acc[1][2] = MFMA_I8(a1, b2, acc[1][2]);
        acc[1][3] = MFMA_I8(a1, b3, acc[1][3]);
        __builtin_amdgcn_s_setprio(0);
        __builtin_amdgcn_s_barrier();

        // ---------- P2: t0, m2-3 ----------
        a0 = ld16(Tb0 + aoff + 2048); a1 = ld16(Tb0 + aoff + 3072);
        SA8(t1, 1);
        if (full) { SB8(t0 + 2); WAIT_VM1(); } else { WAIT_VM0(); }
        __builtin_amdgcn_s_barrier();
        WAIT_LGKM0();
        __builtin_amdgcn_s_setprio(1);
        acc[2][0] = MFMA_I8(a0, b0, acc[2][0]);
        acc[2][1] = MFMA_I8(a0, b1, acc[2][1]);
        acc[2][2] = MFMA_I8(a0, b2, acc[2][2]);
        acc[2][3] = MFMA_I8(a0, b3, acc[2][3]);
        acc[3][0] = MFMA_I8(a1, b0, acc[3][0]);
        acc[3][1] = MFMA_I8(a1, b1, acc[3][1]);
        acc[3][2] = MFMA_I8(a1, b2, acc[3][2]);
        acc[3][3] = MFMA_I8(a1, b3, acc[3][3]);
        __builtin_amdgcn_s_setprio(0);
        __builtin_amdgcn_s_barrier();

        // ---------- P3: t1, m0-1 ----------
        b0 = ld16(Tb1 + boff);        b1 = ld16(Tb1 + boff + 1024);
        b2 = ld16(Tb1 + boff + 2048); b3 = ld16(Tb1 + boff + 3072);
        a0 = ld16(Tb1 + aoff);        a1 = ld16(Tb1 + aoff + 1024);
        if (full) SA8(t0 + 2, 0);
        __builtin_amdgcn_s_barrier();
        WAIT_LGKM0();
        __builtin_amdgcn_s_setprio(1);
        acc[0][0] = MFMA_I8(a0, b0, acc[0][0]);
        acc[0][1] = MFMA_I8(a0, b1, acc[0][1]);
        acc[0][2] = MFMA_I8(a0, b2, acc[0][2]);
        acc[0][3] = MFMA_I8(a0, b3, acc[0][3]);
        acc[1][0] = MFMA_I8(a1, b0, acc[1][0]);
        acc[1][1] = MFMA_I8(a1, b1, acc[1][1]);
        acc[1][2] = MFMA_I8(a1, b2, acc[1][2]);
        acc[1][3] = MFMA_I8(a1, b3, acc[1][3]);
        __builtin_amdgcn_s_setprio(0);
        __builtin_amdgcn_s_barrier();

        // ---------- P4: t1, m2-3 ----------
        a0 = ld16(Tb1 + aoff + 2048); a1 = ld16(Tb1 + aoff + 3072);
        if (full) { SA8(t0 + 2, 1); SB8(t1 + 2); WAIT_VM1(); } else { WAIT_VM0(); }
        __builtin_amdgcn_s_barrier();
        WAIT_LGKM0();
        __builtin_amdgcn_s_setprio(1);
        acc[2][0] = MFMA_I8(a0, b0, acc[2][0]);
        acc[2][1] = MFMA_I8(a0, b1, acc[2][1]);
        acc[2][2] = MFMA_I8(a0, b2, acc[2][2]);
        acc[2][3] = MFMA_I8(a0, b3, acc[2][3]);
        acc[3][0] = MFMA_I8(a1, b0, acc[3][0]);
        acc[3][1] = MFMA_I8(a1, b1, acc[3][1]);
        acc[3][2] = MFMA_I8(a1, b2, acc[3][2]);
        acc[3][3] = MFMA_I8(a1, b3, acc[3][3]);
        __builtin_amdgcn_s_setprio(0);
        __builtin_amdgcn_s_barrier();
    }
#undef BUF8
#undef SA8
#undef SB8

#pragma unroll
    for (int m = 0; m < 4; ++m)
#pragma unroll
        for (int n = 0; n < 4; ++n)
#pragma unroll
            for (int r = 0; r < 4; ++r) {
                int grow = m0 + wr * 64 + m * 16 + lh * 4 + r;
                int gcol = n0 + wc * 64 + n * 16 + l4;
                float y = alpha * (float)acc[m][n][r] + bias[gcol];
                float v = rintf(y);
                v = fminf(fmaxf(v, -128.0f), 127.0f);
                out[(size_t)grow * N + gcol] = (i8)v;
            }
}

// fused Q/K/V projection (8-phase core): blockIdx.z selects weight/bias/dst
__global__ __launch_bounds__(512, 4) void k_gemm_qkv(
    const i8* __restrict__ X,
    const i8* __restrict__ w0, const i8* __restrict__ w1, const i8* __restrict__ w2,
    const float* __restrict__ b0, const float* __restrict__ b1, const float* __restrict__ b2,
    i8* __restrict__ o0, i8* __restrict__ o1, i8* __restrict__ o2,
    float alpha, int M, int N, int K)
{
    __shared__ __align__(16) i8 lds[2 * 24576];
    int z = blockIdx.z;
    const i8* W = (z == 0) ? w0 : (z == 1) ? w1 : w2;
    const float* bias = (z == 0) ? b0 : (z == 1) ? b1 : b2;
    i8* out = (z == 0) ? o0 : (z == 1) ? o1 : o2;
    gemm8p_core(X, W, bias, out, alpha, M, N, K, lds);
}

__global__ __launch_bounds__(512, 4) void k_gemm_out(
    const i8* __restrict__ X, const i8* __restrict__ W, const float* __restrict__ bias,
    float* __restrict__ out, float alpha, int M, int N, int K)
{
    __shared__ __align__(16) i8 lds[3 * 24576];
    gemm_core<false>(X, W, bias, out, alpha, M, N, K, lds);
}

// ---------------- rope: (B,S,H,D) i8 -> (B,H,S,D) i8, rotary on d<64 ----------------
__global__ void k_rope(const i8* __restrict__ qin, const i8* __restrict__ kin,
                       i8* __restrict__ qout, i8* __restrict__ kout,
                       const float* __restrict__ sin_t, const float* __restrict__ cos_t)
{
    const i8* in = blockIdx.y ? kin : qin;
    i8* outp = blockIdx.y ? kout : qout;
    int row = blockIdx.x * 2 + (threadIdx.x >> 7);   // (b*S + s)*H + h
    int i = threadIdx.x & 127;
    int b = row / (S_ * H_);
    int s = (row / H_) % S_;
    int h = row % H_;
    const i8* src = in + (size_t)row * D_ + i * 2;
    i8 x1 = src[0], x2 = src[1];
    i8 o1, o2;
    if (i < 32) {
        float c = cos_t[s * 32 + i], sn = sin_t[s * 32 + i];
        float f1 = (float)x1, f2 = (float)x2;
        float r0 = __fadd_rn(__fmul_rn(f1, c), __fmul_rn(-f2, sn));
        float r1 = __fadd_rn(__fmul_rn(f2, c), __fmul_rn(f1, sn));
        r0 = truncf(fminf(fmaxf(r0, -128.0f), 127.0f));
        r1 = truncf(fminf(fmaxf(r1, -128.0f), 127.0f));
        o1 = (i8)r0; o2 = (i8)r1;
    } else { o1 = x1; o2 = x2; }
    size_t ob = ((size_t)(b * H_ + h) * S_ + s) * D_ + i * 2;
    outp[ob] = o1; outp[ob + 1] = o2;
}

// ---------------- V transpose: (B,S,H,D) -> (B,H,D,S) ----------------
__global__ void k_vtrans(const i8* __restrict__ vin, i8* __restrict__ vout) {
    __shared__ int tile[64][17];
    int bh = blockIdx.z;
    int b = bh >> 4, h = bh & 15;
    int s0 = blockIdx.x * 64, d0 = blockIdx.y * 64;
    int t = threadIdx.x;
    {
        int sr = t >> 2, dq = (t & 3) * 16;
        int32x4 v = ld16(vin + ((size_t)(b * S_ + s0 + sr) * H_ + h) * D_ + d0 + dq);
#pragma unroll
        for (int j = 0; j < 4; ++j) tile[sr][dq / 4 + j] = v[j];
    }
    __syncthreads();
    {
        int dr = t >> 2, sq = (t & 3) * 16;
        union { int32x4 v; i8 b[16]; } u;
        const i8* tb = reinterpret_cast<const i8*>(tile);
#pragma unroll
        for (int j = 0; j < 16; ++j) u.b[j] = tb[(sq + j) * 68 + dr];
        *reinterpret_cast<int32x4*>(vout + ((size_t)bh * D_ + d0 + dr) * S_ + s0 + sq) = u.v;
    }
}

// ---------------- fused int8 attention (R8 version) ----------------
struct AttnShared {
    float slx[4][32];
    float r127[32];
    __align__(16) i8 plds[32][80];
};

__device__ __forceinline__ void attn_chunk(int qc, int bh, int tid,
    const i8* __restrict__ Qh, const i8* __restrict__ Kb, const i8* __restrict__ Vb,
    i8* __restrict__ O, AttnShared& sh)
{
    const float C2 = 1.25e-5f * 1.44269504088896f;   // A_QK/16 * log2(e)
    const float APV = 1.0f / 127.0f;
    const int lane = tid & 63, wave = tid >> 6;
    const int l4 = lane & 15, lh = lane >> 4;
    const i8* Qb = Qh + (size_t)(qc * 32) * D_;
    const int nt = (qc * 32 + 31) / 64 + 1;

    int32x4 aq[2][4];
#pragma unroll
    for (int m = 0; m < 2; ++m)
#pragma unroll
        for (int kk = 0; kk < 4; ++kk)
            aq[m][kk] = ld16(Qb + (size_t)(m * 16 + l4) * D_ + kk * 64 + lh * 16);

    float sum_[2][4];
#pragma unroll
    for (int m = 0; m < 2; ++m)
#pragma unroll
        for (int r = 0; r < 4; ++r) sum_[m][r] = 0.0f;

    for (int kt = 0; kt < nt; ++kt) {
        int cb = kt * 64 + wave * 16;
        int32x4 acc0 = int32x4{0,0,0,0}, acc1 = int32x4{0,0,0,0};
#pragma unroll
        for (int kk = 0; kk < 4; ++kk) {
            int32x4 bf = ld16(Kb + (size_t)(cb + l4) * D_ + kk * 64 + lh * 16);
            acc0 = MFMA_I8(aq[0][kk], bf, acc0);
            acc1 = MFMA_I8(aq[1][kk], bf, acc1);
        }
        int gcol = cb + l4;
#pragma unroll
        for (int m = 0; m < 2; ++m) {
            int32x4 accm = m ? acc1 : acc0;
#pragma unroll
            for (int r = 0; r < 4; ++r) {
                int grow = qc * 32 + m * 16 + lh * 4 + r;
                float e = (gcol <= grow) ? exp2f((float)accm[r] * C2) : 0.0f;
                sum_[m][r] += e;
            }
        }
    }

#pragma unroll
    for (int m = 0; m < 2; ++m)
#pragma unroll
        for (int r = 0; r < 4; ++r) {
            float s = sum_[m][r];
            s += __shfl_xor(s, 1);
            s += __shfl_xor(s, 2);
            s += __shfl_xor(s, 4);
            s += __shfl_xor(s, 8);
            if (l4 == 0) sh.slx[wave][m * 16 + lh * 4 + r] = s;
        }
    __syncthreads();
    if (tid < 32)
        sh.r127[tid] = 127.0f /
            (sh.slx[0][tid] + sh.slx[1][tid] + sh.slx[2][tid] + sh.slx[3][tid]);
    __syncthreads();

    int32x4 oacc[2][4];
#pragma unroll
    for (int m = 0; m < 2; ++m)
#pragma unroll
        for (int n = 0; n < 4; ++n) oacc[m][n] = int32x4{0, 0, 0, 0};

    for (int kt = 0; kt < nt; ++kt) {
        int cb = kt * 64 + wave * 16;
        int32x4 acc0 = int32x4{0,0,0,0}, acc1 = int32x4{0,0,0,0};
#pragma unroll
        for (int kk = 0; kk < 4; ++kk) {
            int32x4 bf = ld16(Kb + (size_t)(cb + l4) * D_ + kk * 64 + lh * 16);
            acc0 = MFMA_I8(aq[0][kk], bf, acc0);
            acc1 = MFMA_I8(aq[1][kk], bf, acc1);
        }
        int gcol = cb + l4;
        i8 pv[2][4];
#pragma unroll
        for (int m = 0; m < 2; ++m) {
            int32x4 accm = m ? acc1 : acc0;
#pragma unroll
            for (int r = 0; r < 4; ++r) {
                int rowi = m * 16 + lh * 4 + r;
                int grow = qc * 32 + rowi;
                float e = (gcol <= grow) ? exp2f((float)accm[r] * C2) : 0.0f;
                pv[m][r] = (i8)(int)rintf(e * sh.r127[rowi]);
            }
        }
        __syncthreads();
#pragma unroll
        for (int m = 0; m < 2; ++m)
#pragma unroll
            for (int r = 0; r < 4; ++r)
                sh.plds[m * 16 + lh * 4 + r][wave * 16 + l4] = pv[m][r];
        __syncthreads();
        int32x4 a0 = ld16(&sh.plds[l4][lh * 16]);
        int32x4 a1 = ld16(&sh.plds[16 + l4][lh * 16]);
#pragma unroll
        for (int n = 0; n < 4; ++n) {
            int32x4 bf = ld16(Vb + (size_t)(wave * 64 + n * 16 + l4) * S_ + kt * 64 + lh * 16);
            oacc[0][n] = MFMA_I8(a0, bf, oacc[0][n]);
            oacc[1][n] = MFMA_I8(a1, bf, oacc[1][n]);
        }
    }

    int b = bh >> 4, h = bh & 15;
#pragma unroll
    for (int m = 0; m < 2; ++m)
#pragma unroll
        for (int r = 0; r < 4; ++r) {
            int s = qc * 32 + m * 16 + lh * 4 + r;
#pragma unroll
            for (int n = 0; n < 4; ++n) {
                float o = rintf(APV * (float)oacc[m][n][r]);
                o = fminf(fmaxf(o, -128.0f), 127.0f);
                O[((size_t)(b * S_ + s) * H_ + h) * D_ + wave * 64 + n * 16 + l4] = (i8)o;
            }
        }
}

// Pair chunks (p, 31-p): every block does ~17 k-tiles -> uniform runtime.
__global__ __launch_bounds__(256) void k_attn(const i8* __restrict__ Q, const i8* __restrict__ K,
                                              const i8* __restrict__ V, i8* __restrict__ O)
{
    __shared__ AttnShared sh;
    int bh = blockIdx.x;
    int p = blockIdx.y;
    int tid = threadIdx.x;
    const i8* Qh = Q + (size_t)bh * S_ * D_;
    const i8* Kb = K + (size_t)bh * S_ * D_;
    const i8* Vb = V + (size_t)bh * D_ * S_;
    attn_chunk((S_ / 32 - 1) - p, bh, tid, Qh, Kb, Vb, O, sh);
    attn_chunk(p, bh, tid, Qh, Kb, Vb, O, sh);
}

extern "C" void kernel_launch(void* const* d_in, const int* in_sizes, int n_in,
                              void* d_out, int out_size, void* d_ws, size_t ws_size,
                              hipStream_t stream) {
    const float* hs = (const float*)d_in[0];
    const float* Wq = (const float*)d_in[1];
    const float* Wk = (const float*)d_in[2];
    const float* Wv = (const float*)d_in[3];
    const float* Wo = (const float*)d_in[4];
    const float* bq = (const float*)d_in[5];
    const float* bk = (const float*)d_in[6];
    const float* bv = (const float*)d_in[7];
    const float* bo = (const float*)d_in[8];
    float* out = (float*)d_out;

    size_t off = 0;
    char* wsb = (char*)d_ws;
    auto carve = [&](size_t bytes) { char* p = wsb + off; off += (bytes + 255) & ~(size_t)255; return p; };
    const size_t ME = (size_t)B_ * S_ * E_;   // 8.4 MB
    const size_t EE = (size_t)E_ * E_;        // 16.8 MB
    i8* x8  = (i8*)carve(ME);
    i8* wq8 = (i8*)carve(EE);
    i8* wk8 = (i8*)carve(EE);
    i8* wv8 = (i8*)carve(EE);
    i8* wo8 = (i8*)carve(EE);
    i8* q8  = (i8*)carve(ME);
    i8* k8  = (i8*)carve(ME);
    i8* v8  = (i8*)carve(ME);
    i8* qr  = (i8*)carve(ME);
    i8* kr  = (i8*)carve(ME);
    i8* vt  = (i8*)carve(ME);
    i8* o8  = (i8*)carve(ME);
    float* sin_t = (float*)carve((size_t)S_ * 32 * 4);
    float* cos_t = (float*)carve((size_t)S_ * 32 * 4);

    int n4_me = (int)(ME / 4), n4_ee = (int)(EE / 4);
    k_f32_to_i8<<<(n4_me + 255) / 256, 256, 0, stream>>>(hs, x8, n4_me);
    k_w_to_i8<<<dim3((n4_ee + 255) / 256, 4), 256, 0, stream>>>(
        Wq, Wk, Wv, Wo, wq8, wk8, wv8, wo8, n4_ee);
    k_sincos<<<(S_ * 32 + 255) / 256, 256, 0, stream>>>(sin_t, cos_t);

    const int M = B_ * S_, N = E_, Kd = E_;
    const int nwg = (M / 256) * (N / 128);   // 256 blocks per z
    k_gemm_qkv<<<dim3(nwg, 1, 3), 512, 0, stream>>>(
        x8, wq8, wk8, wv8, bq, bk, bv, q8, k8, v8, 0.00012f, M, N, Kd);

    k_rope<<<dim3((B_ * S_ * H_) / 2, 2), 256, 0, stream>>>(q8, k8, qr, kr, sin_t, cos_t);
    k_vtrans<<<dim3(S_ / 64, D_ / 64, B_ * H_), 256, 0, stream>>>(v8, vt);
    k_attn<<<dim3(B_ * H_, S_ / 64), 256, 0, stream>>>(qr, kr, vt, o8);

    k_gemm_out<<<nwg, 512, 0, stream>>>(o8, wo8, bo, out, 0.01f, M, N, Kd);
}

// Round 14
// 298.784 us; speedup vs baseline: 1.0757x; 1.0585x over previous
//
#include <hip/hip_runtime.h>
#include <hip/hip_bf16.h>

typedef int int32x4 __attribute__((ext_vector_type(4)));
typedef signed char i8;

#define B_ 2
#define S_ 1024
#define E_ 4096
#define H_ 16
#define D_ 256

#define MFMA_I8(a, b, c) __builtin_amdgcn_mfma_i32_16x16x64_i8((a), (b), (c), 0, 0, 0)

__device__ __forceinline__ int32x4 ld16(const void* p) {
    return *reinterpret_cast<const int32x4*>(p);
}

// async global->LDS, 16B per lane. LDS dest = wave-uniform base + lane*16.
__device__ __forceinline__ void gload16(const void* g, void* l) {
    __builtin_amdgcn_global_load_lds(
        (const __attribute__((address_space(1))) void*)g,
        (__attribute__((address_space(3))) void*)l, 16, 0, 0);
}

#define WAIT_VM3()  asm volatile("s_waitcnt vmcnt(3)" ::: "memory")
#define WAIT_VM0()  asm volatile("s_waitcnt vmcnt(0)" ::: "memory")
#define COMPILER_FENCE() asm volatile("" ::: "memory")

// ---------------- fp32 (integer-valued) -> int8, coalesced ----------------
__device__ __forceinline__ int pack4(float4 f) {
    union { int w; i8 b[4]; } u;
    u.b[0] = (i8)f.x; u.b[1] = (i8)f.y; u.b[2] = (i8)f.z; u.b[3] = (i8)f.w;
    return u.w;
}

__global__ void k_f32_to_i8(const float* __restrict__ src, i8* __restrict__ dst, int n4) {
    int i = blockIdx.x * blockDim.x + threadIdx.x;
    if (i >= n4) return;
    reinterpret_cast<int*>(dst)[i] = pack4(reinterpret_cast<const float4*>(src)[i]);
}

// 4 weight matrices in one launch (blockIdx.y selects matrix)
__global__ void k_w_to_i8(const float* __restrict__ w0, const float* __restrict__ w1,
                          const float* __restrict__ w2, const float* __restrict__ w3,
                          i8* __restrict__ d0, i8* __restrict__ d1,
                          i8* __restrict__ d2, i8* __restrict__ d3, int n4) {
    int i = blockIdx.x * blockDim.x + threadIdx.x;
    if (i >= n4) return;
    const float* src = (blockIdx.y == 0) ? w0 : (blockIdx.y == 1) ? w1 : (blockIdx.y == 2) ? w2 : w3;
    i8* dst = (blockIdx.y == 0) ? d0 : (blockIdx.y == 1) ? d1 : (blockIdx.y == 2) ? d2 : d3;
    reinterpret_cast<int*>(dst)[i] = pack4(reinterpret_cast<const float4*>(src)[i]);
}

// ---------------- sin/cos table [S][32] ----------------
__global__ void k_sincos(float* __restrict__ sin_t, float* __restrict__ cos_t) {
    int idx = blockIdx.x * blockDim.x + threadIdx.x;
    if (idx >= S_ * 32) return;
    int s = idx >> 5, i = idx & 31;
    float ex = (float)(2 * i) / 64.0f;
    float invf = 1.0f / powf(10000.0f, ex);
    float arg = (float)s * invf;
    sin_t[idx] = (float)sin((double)arg);
    cos_t[idx] = (float)cos((double)arg);
}

// ============== R8 GEMM core (known-good) ==============
// BM=256, BN=128, BK=64, 8 waves (4M x 2N), per-wave 64x64, triple-buffered
// 72KB LDS, counted vmcnt(3), XOR granule swizzle (0 conflicts verified).
// EPI: 0 = fp32 row-major [M][N];  1 = i8 row-major [M][N];
//      2 = QK rope epilogue: quantize -> rotary(d<64) -> trunc-clip ->
//          write i8 to (B,H,S,D). Rotary partner via __shfl_xor(.,1)
//          (pair lanes l4 even/odd hold d, d^1); d<64 is wave-uniform per n.
template<int EPI>
__device__ __forceinline__ void gemm_core(
    const i8* __restrict__ X, const i8* __restrict__ W, const float* __restrict__ bias,
    void* __restrict__ out, float alpha, int M, int N, int K, i8* lds,
    const float* __restrict__ sin_t, const float* __restrict__ cos_t)
{
    const int nt = K >> 6;
    const int nwg = (M >> 8) * (N >> 7);
    const int q = nwg >> 3;
    const int lin = blockIdx.x;
    const int wg = (lin & 7) * q + (lin >> 3);
    const int nbm = M >> 8;
    const int m0 = (wg % nbm) * 256, n0 = (wg / nbm) * 128;

    const int tid = threadIdx.x, lane = tid & 63, wave = tid >> 6;
    const int wr = wave >> 1, wc = wave & 1, l4 = lane & 15, lh = lane >> 4;

    const int g4 = lh ^ ((l4 >> 1) & 3);
    const int aoff = (wr * 64 + l4) * 64 + g4 * 16;
    const int boff = 16384 + (wc * 64 + l4) * 64 + g4 * 16;

    const int srow = tid >> 2;
    const int sg = (tid & 3) ^ ((tid >> 3) & 3);
    const i8* Asrc = X + (size_t)(m0 + srow) * K + sg * 16;
    const i8* Bsrc = W + (size_t)(n0 + srow) * K + sg * 16;
    const size_t rstep = (size_t)128 * K;
    const int ldst = wave * 1024;

#define BUF3(t_) (lds + ((t_) % 3) * 24576)
#define STAGE3(t_) do { int kb_ = (t_) * 64; i8* lb_ = BUF3(t_);             \
        gload16(Asrc + kb_,         lb_ + ldst);                             \
        gload16(Asrc + rstep + kb_, lb_ + 8192 + ldst);                      \
        gload16(Bsrc + kb_,         lb_ + 16384 + ldst); } while (0)

    int32x4 acc[4][4];
#pragma unroll
    for (int m = 0; m < 4; ++m)
#pragma unroll
        for (int n = 0; n < 4; ++n) acc[m][n] = int32x4{0, 0, 0, 0};

    STAGE3(0);
    STAGE3(1);

    for (int t = 0; t < nt; ++t) {
        const i8* Tb = BUF3(t);
        if (t + 1 < nt) { WAIT_VM3(); } else { WAIT_VM0(); }
        __builtin_amdgcn_s_barrier();
        COMPILER_FENCE();

        if (t + 2 < nt) STAGE3(t + 2);

        int32x4 a0, a1, a2, a3, b0, b1, b2, b3;
        a0 = ld16(Tb + aoff);
        b0 = ld16(Tb + boff);        b1 = ld16(Tb + boff + 1024);
        b2 = ld16(Tb + boff + 2048); b3 = ld16(Tb + boff + 3072);
        a1 = ld16(Tb + aoff + 1024);
        a2 = ld16(Tb + aoff + 2048); a3 = ld16(Tb + aoff + 3072);
        __builtin_amdgcn_s_setprio(1);
        acc[0][0] = MFMA_I8(a0, b0, acc[0][0]);
        acc[0][1] = MFMA_I8(a0, b1, acc[0][1]);
        acc[0][2] = MFMA_I8(a0, b2, acc[0][2]);
        acc[0][3] = MFMA_I8(a0, b3, acc[0][3]);
        acc[1][0] = MFMA_I8(a1, b0, acc[1][0]);
        acc[1][1] = MFMA_I8(a1, b1, acc[1][1]);
        acc[1][2] = MFMA_I8(a1, b2, acc[1][2]);
        acc[1][3] = MFMA_I8(a1, b3, acc[1][3]);
        acc[2][0] = MFMA_I8(a2, b0, acc[2][0]);
        acc[2][1] = MFMA_I8(a2, b1, acc[2][1]);
        acc[2][2] = MFMA_I8(a2, b2, acc[2][2]);
        acc[2][3] = MFMA_I8(a2, b3, acc[2][3]);
        acc[3][0] = MFMA_I8(a3, b0, acc[3][0]);
        acc[3][1] = MFMA_I8(a3, b1, acc[3][1]);
        acc[3][2] = MFMA_I8(a3, b2, acc[3][2]);
        acc[3][3] = MFMA_I8(a3, b3, acc[3][3]);
        __builtin_amdgcn_s_setprio(0);
    }
#undef BUF3
#undef STAGE3

#pragma unroll
    for (int m = 0; m < 4; ++m)
#pragma unroll
        for (int n = 0; n < 4; ++n) {
            // d-block is uniform for this (m,n) across the wave
#pragma unroll
            for (int r = 0; r < 4; ++r) {
                int grow = m0 + wr * 64 + m * 16 + lh * 4 + r;
                int gcol = n0 + wc * 64 + n * 16 + l4;
                float y = alpha * (float)acc[m][n][r] + bias[gcol];
                if (EPI == 0) {
                    reinterpret_cast<float*>(out)[(size_t)grow * N + gcol] = y;
                } else if (EPI == 1) {
                    float v = rintf(y);
                    v = fminf(fmaxf(v, -128.0f), 127.0f);
                    reinterpret_cast<i8*>(out)[(size_t)grow * N + gcol] = (i8)v;
                } else {
                    // quantize (round, clip) first — matches _linear_i8
                    float xq = rintf(y);
                    xq = fminf(fmaxf(xq, -128.0f), 127.0f);
                    int d = gcol & 255;
                    float partner = __shfl_xor(xq, 1);   // lane pair l4^1 = d^1
                    float o = xq;
                    if (d < 64) {                         // wave-uniform branch
                        int b = grow >> 10, s = grow & 1023;
                        (void)b;
                        int i = d >> 1;
                        float c = cos_t[s * 32 + i], sn = sin_t[s * 32 + i];
                        float r0;
                        if ((d & 1) == 0)
                            r0 = __fadd_rn(__fmul_rn(xq, c), __fmul_rn(-partner, sn));
                        else
                            r0 = __fadd_rn(__fmul_rn(xq, c), __fmul_rn(partner, sn));
                        o = truncf(fminf(fmaxf(r0, -128.0f), 127.0f));
                    }
                    int b = grow >> 10, s = grow & 1023, h = gcol >> 8;
                    reinterpret_cast<i8*>(out)[
                        ((size_t)(b * H_ + h) * S_ + s) * D_ + d] = (i8)o;
                }
            }
        }
}

// fused Q/K/V projection: z=0,1 -> rope epilogue to (B,H,S,D); z=2 plain i8
__global__ __launch_bounds__(512, 4) void k_gemm_qkv(
    const i8* __restrict__ X,
    const i8* __restrict__ w0, const i8* __restrict__ w1, const i8* __restrict__ w2,
    const float* __restrict__ b0, const float* __restrict__ b1, const float* __restrict__ b2,
    i8* __restrict__ o0, i8* __restrict__ o1, i8* __restrict__ o2,
    const float* __restrict__ sin_t, const float* __restrict__ cos_t,
    float alpha, int M, int N, int K)
{
    __shared__ __align__(16) i8 lds[3 * 24576];
    int z = blockIdx.z;
    const i8* W = (z == 0) ? w0 : (z == 1) ? w1 : w2;
    const float* bias = (z == 0) ? b0 : (z == 1) ? b1 : b2;
    i8* out = (z == 0) ? o0 : (z == 1) ? o1 : o2;
    if (z < 2)
        gemm_core<2>(X, W, bias, out, alpha, M, N, K, lds, sin_t, cos_t);
    else
        gemm_core<1>(X, W, bias, out, alpha, M, N, K, lds, nullptr, nullptr);
}

__global__ __launch_bounds__(512, 4) void k_gemm_out(
    const i8* __restrict__ X, const i8* __restrict__ W, const float* __restrict__ bias,
    float* __restrict__ out, float alpha, int M, int N, int K)
{
    __shared__ __align__(16) i8 lds[3 * 24576];
    gemm_core<0>(X, W, bias, out, alpha, M, N, K, lds, nullptr, nullptr);
}

// ---------------- V transpose: (B,S,H,D) -> (B,H,D,S) ----------------
__global__ void k_vtrans(const i8* __restrict__ vin, i8* __restrict__ vout) {
    __shared__ int tile[64][17];
    int bh = blockIdx.z;
    int b = bh >> 4, h = bh & 15;
    int s0 = blockIdx.x * 64, d0 = blockIdx.y * 64;
    int t = threadIdx.x;
    {
        int sr = t >> 2, dq = (t & 3) * 16;
        int32x4 v = ld16(vin + ((size_t)(b * S_ + s0 + sr) * H_ + h) * D_ + d0 + dq);
#pragma unroll
        for (int j = 0; j < 4; ++j) tile[sr][dq / 4 + j] = v[j];
    }
    __syncthreads();
    {
        int dr = t >> 2, sq = (t & 3) * 16;
        union { int32x4 v; i8 b[16]; } u;
        const i8* tb = reinterpret_cast<const i8*>(tile);
#pragma unroll
        for (int j = 0; j < 16; ++j) u.b[j] = tb[(sq + j) * 68 + dr];
        *reinterpret_cast<int32x4*>(vout + ((size_t)bh * D_ + d0 + dr) * S_ + s0 + sq) = u.v;
    }
}

// ---------------- fused int8 attention (R8 version) ----------------
// NOTE: V is produced by k_gemm_qkv z=2 in (B,S,H,D) row-major [M][E] form,
// then k_vtrans -> (B,H,D,S).
struct AttnShared {
    float slx[4][32];
    float r127[32];
    __align__(16) i8 plds[32][80];
};

__device__ __forceinline__ void attn_chunk(int qc, int bh, int tid,
    const i8* __restrict__ Qh, const i8* __restrict__ Kb, const i8* __restrict__ Vb,
    i8* __restrict__ O, AttnShared& sh)
{
    const float C2 = 1.25e-5f * 1.44269504088896f;   // A_QK/16 * log2(e)
    const float APV = 1.0f / 127.0f;
    const int lane = tid & 63, wave = tid >> 6;
    const int l4 = lane & 15, lh = lane >> 4;
    const i8* Qb = Qh + (size_t)(qc * 32) * D_;
    const int nt = (qc * 32 + 31) / 64 + 1;

    int32x4 aq[2][4];
#pragma unroll
    for (int m = 0; m < 2; ++m)
#pragma unroll
        for (int kk = 0; kk < 4; ++kk)
            aq[m][kk] = ld16(Qb + (size_t)(m * 16 + l4) * D_ + kk * 64 + lh * 16);

    float sum_[2][4];
#pragma unroll
    for (int m = 0; m < 2; ++m)
#pragma unroll
        for (int r = 0; r < 4; ++r) sum_[m][r] = 0.0f;

    for (int kt = 0; kt < nt; ++kt) {
        int cb = kt * 64 + wave * 16;
        int32x4 acc0 = int32x4{0,0,0,0}, acc1 = int32x4{0,0,0,0};
#pragma unroll
        for (int kk = 0; kk < 4; ++kk) {
            int32x4 bf = ld16(Kb + (size_t)(cb + l4) * D_ + kk * 64 + lh * 16);
            acc0 = MFMA_I8(aq[0][kk], bf, acc0);
            acc1 = MFMA_I8(aq[1][kk], bf, acc1);
        }
        int gcol = cb + l4;
#pragma unroll
        for (int m = 0; m < 2; ++m) {
            int32x4 accm = m ? acc1 : acc0;
#pragma unroll
            for (int r = 0; r < 4; ++r) {
                int grow = qc * 32 + m * 16 + lh * 4 + r;
                float e = (gcol <= grow) ? exp2f((float)accm[r] * C2) : 0.0f;
                sum_[m][r] += e;
            }
        }
    }

#pragma unroll
    for (int m = 0; m < 2; ++m)
#pragma unroll
        for (int r = 0; r < 4; ++r) {
            float s = sum_[m][r];
            s += __shfl_xor(s, 1);
            s += __shfl_xor(s, 2);
            s += __shfl_xor(s, 4);
            s += __shfl_xor(s, 8);
            if (l4 == 0) sh.slx[wave][m * 16 + lh * 4 + r] = s;
        }
    __syncthreads();
    if (tid < 32)
        sh.r127[tid] = 127.0f /
            (sh.slx[0][tid] + sh.slx[1][tid] + sh.slx[2][tid] + sh.slx[3][tid]);
    __syncthreads();

    int32x4 oacc[2][4];
#pragma unroll
    for (int m = 0; m < 2; ++m)
#pragma unroll
        for (int n = 0; n < 4; ++n) oacc[m][n] = int32x4{0, 0, 0, 0};

    for (int kt = 0; kt < nt; ++kt) {
        int cb = kt * 64 + wave * 16;
        int32x4 acc0 = int32x4{0,0,0,0}, acc1 = int32x4{0,0,0,0};
#pragma unroll
        for (int kk = 0; kk < 4; ++kk) {
            int32x4 bf = ld16(Kb + (size_t)(cb + l4) * D_ + kk * 64 + lh * 16);
            acc0 = MFMA_I8(aq[0][kk], bf, acc0);
            acc1 = MFMA_I8(aq[1][kk], bf, acc1);
        }
        int gcol = cb + l4;
        i8 pv[2][4];
#pragma unroll
        for (int m = 0; m < 2; ++m) {
            int32x4 accm = m ? acc1 : acc0;
#pragma unroll
            for (int r = 0; r < 4; ++r) {
                int rowi = m * 16 + lh * 4 + r;
                int grow = qc * 32 + rowi;
                float e = (gcol <= grow) ? exp2f((float)accm[r] * C2) : 0.0f;
                pv[m][r] = (i8)(int)rintf(e * sh.r127[rowi]);
            }
        }
        __syncthreads();
#pragma unroll
        for (int m = 0; m < 2; ++m)
#pragma unroll
            for (int r = 0; r < 4; ++r)
                sh.plds[m * 16 + lh * 4 + r][wave * 16 + l4] = pv[m][r];
        __syncthreads();
        int32x4 a0 = ld16(&sh.plds[l4][lh * 16]);
        int32x4 a1 = ld16(&sh.plds[16 + l4][lh * 16]);
#pragma unroll
        for (int n = 0; n < 4; ++n) {
            int32x4 bf = ld16(Vb + (size_t)(wave * 64 + n * 16 + l4) * S_ + kt * 64 + lh * 16);
            oacc[0][n] = MFMA_I8(a0, bf, oacc[0][n]);
            oacc[1][n] = MFMA_I8(a1, bf, oacc[1][n]);
        }
    }

    int b = bh >> 4, h = bh & 15;
#pragma unroll
    for (int m = 0; m < 2; ++m)
#pragma unroll
        for (int r = 0; r < 4; ++r) {
            int s = qc * 32 + m * 16 + lh * 4 + r;
#pragma unroll
            for (int n = 0; n < 4; ++n) {
                float o = rintf(APV * (float)oacc[m][n][r]);
                o = fminf(fmaxf(o, -128.0f), 127.0f);
                O[((size_t)(b * S_ + s) * H_ + h) * D_ + wave * 64 + n * 16 + l4] = (i8)o;
            }
        }
}

// Pair chunks (p, 31-p): every block does ~17 k-tiles -> uniform runtime.
__global__ __launch_bounds__(256) void k_attn(const i8* __restrict__ Q, const i8* __restrict__ K,
                                              const i8* __restrict__ V, i8* __restrict__ O)
{
    __shared__ AttnShared sh;
    int bh = blockIdx.x;
    int p = blockIdx.y;
    int tid = threadIdx.x;
    const i8* Qh = Q + (size_t)bh * S_ * D_;
    const i8* Kb = K + (size_t)bh * S_ * D_;
    const i8* Vb = V + (size_t)bh * D_ * S_;
    attn_chunk((S_ / 32 - 1) - p, bh, tid, Qh, Kb, Vb, O, sh);
    attn_chunk(p, bh, tid, Qh, Kb, Vb, O, sh);
}

extern "C" void kernel_launch(void* const* d_in, const int* in_sizes, int n_in,
                              void* d_out, int out_size, void* d_ws, size_t ws_size,
                              hipStream_t stream) {
    const float* hs = (const float*)d_in[0];
    const float* Wq = (const float*)d_in[1];
    const float* Wk = (const float*)d_in[2];
    const float* Wv = (const float*)d_in[3];
    const float* Wo = (const float*)d_in[4];
    const float* bq = (const float*)d_in[5];
    const float* bk = (const float*)d_in[6];
    const float* bv = (const float*)d_in[7];
    const float* bo = (const float*)d_in[8];
    float* out = (float*)d_out;

    size_t off = 0;
    char* wsb = (char*)d_ws;
    auto carve = [&](size_t bytes) { char* p = wsb + off; off += (bytes + 255) & ~(size_t)255; return p; };
    const size_t ME = (size_t)B_ * S_ * E_;   // 8.4 MB
    const size_t EE = (size_t)E_ * E_;        // 16.8 MB
    i8* x8  = (i8*)carve(ME);
    i8* wq8 = (i8*)carve(EE);
    i8* wk8 = (i8*)carve(EE);
    i8* wv8 = (i8*)carve(EE);
    i8* wo8 = (i8*)carve(EE);
    i8* qr  = (i8*)carve(ME);    // (B,H,S,D), rope applied in GEMM epilogue
    i8* kr  = (i8*)carve(ME);    // (B,H,S,D), rope applied in GEMM epilogue
    i8* v8  = (i8*)carve(ME);    // (B,S,H,D) row-major [M][E]
    i8* vt  = (i8*)carve(ME);    // (B,H,D,S)
    i8* o8  = (i8*)carve(ME);
    float* sin_t = (float*)carve((size_t)S_ * 32 * 4);
    float* cos_t = (float*)carve((size_t)S_ * 32 * 4);

    int n4_me = (int)(ME / 4), n4_ee = (int)(EE / 4);
    k_f32_to_i8<<<(n4_me + 255) / 256, 256, 0, stream>>>(hs, x8, n4_me);
    k_w_to_i8<<<dim3((n4_ee + 255) / 256, 4), 256, 0, stream>>>(
        Wq, Wk, Wv, Wo, wq8, wk8, wv8, wo8, n4_ee);
    k_sincos<<<(S_ * 32 + 255) / 256, 256, 0, stream>>>(sin_t, cos_t);

    const int M = B_ * S_, N = E_, Kd = E_;
    const int nwg = (M / 256) * (N / 128);   // 256 blocks per z
    k_gemm_qkv<<<dim3(nwg, 1, 3), 512, 0, stream>>>(
        x8, wq8, wk8, wv8, bq, bk, bv, qr, kr, v8, sin_t, cos_t, 0.00012f, M, N, Kd);

    k_vtrans<<<dim3(S_ / 64, D_ / 64, B_ * H_), 256, 0, stream>>>(v8, vt);
    k_attn<<<dim3(B_ * H_, S_ / 64), 256, 0, stream>>>(qr, kr, vt, o8);

    k_gemm_out<<<nwg, 512, 0, stream>>>(o8, wo8, bo, out, 0.01f, M, N, Kd);
}

// Round 15
// 292.495 us; speedup vs baseline: 1.0989x; 1.0215x over previous
//
#include <hip/hip_runtime.h>
#include <hip/hip_bf16.h>

typedef int int32x4 __attribute__((ext_vector_type(4)));
typedef signed char i8;

#define B_ 2
#define S_ 1024
#define E_ 4096
#define H_ 16
#define D_ 256

#define MFMA_I8(a, b, c) __builtin_amdgcn_mfma_i32_16x16x64_i8((a), (b), (c), 0, 0, 0)

__device__ __forceinline__ int32x4 ld16(const void* p) {
    return *reinterpret_cast<const int32x4*>(p);
}

// async global->LDS, 16B per lane. LDS dest = wave-uniform base + lane*16.
__device__ __forceinline__ void gload16(const void* g, void* l) {
    __builtin_amdgcn_global_load_lds(
        (const __attribute__((address_space(1))) void*)g,
        (__attribute__((address_space(3))) void*)l, 16, 0, 0);
}

#define WAIT_VM3()  asm volatile("s_waitcnt vmcnt(3)" ::: "memory")
#define WAIT_VM0()  asm volatile("s_waitcnt vmcnt(0)" ::: "memory")
#define COMPILER_FENCE() asm volatile("" ::: "memory")

// ---------------- fp32 (integer-valued) -> int8, coalesced ----------------
__device__ __forceinline__ int pack4(float4 f) {
    union { int w; i8 b[4]; } u;
    u.b[0] = (i8)f.x; u.b[1] = (i8)f.y; u.b[2] = (i8)f.z; u.b[3] = (i8)f.w;
    return u.w;
}

__global__ void k_f32_to_i8(const float* __restrict__ src, i8* __restrict__ dst, int n4) {
    int i = blockIdx.x * blockDim.x + threadIdx.x;
    if (i >= n4) return;
    reinterpret_cast<int*>(dst)[i] = pack4(reinterpret_cast<const float4*>(src)[i]);
}

// 4 weight matrices in one launch (blockIdx.y selects matrix)
__global__ void k_w_to_i8(const float* __restrict__ w0, const float* __restrict__ w1,
                          const float* __restrict__ w2, const float* __restrict__ w3,
                          i8* __restrict__ d0, i8* __restrict__ d1,
                          i8* __restrict__ d2, i8* __restrict__ d3, int n4) {
    int i = blockIdx.x * blockDim.x + threadIdx.x;
    if (i >= n4) return;
    const float* src = (blockIdx.y == 0) ? w0 : (blockIdx.y == 1) ? w1 : (blockIdx.y == 2) ? w2 : w3;
    i8* dst = (blockIdx.y == 0) ? d0 : (blockIdx.y == 1) ? d1 : (blockIdx.y == 2) ? d2 : d3;
    reinterpret_cast<int*>(dst)[i] = pack4(reinterpret_cast<const float4*>(src)[i]);
}

// ---------------- sin/cos table [S][32] ----------------
__global__ void k_sincos(float* __restrict__ sin_t, float* __restrict__ cos_t) {
    int idx = blockIdx.x * blockDim.x + threadIdx.x;
    if (idx >= S_ * 32) return;
    int s = idx >> 5, i = idx & 31;
    float ex = (float)(2 * i) / 64.0f;
    float invf = 1.0f / powf(10000.0f, ex);
    float arg = (float)s * invf;
    sin_t[idx] = (float)sin((double)arg);
    cos_t[idx] = (float)cos((double)arg);
}

// ============== R8 GEMM core (known-good) ==============
// BM=256, BN=128, BK=64, 8 waves (4M x 2N), per-wave 64x64, triple-buffered
// 72KB LDS, counted vmcnt(3), XOR granule swizzle (0 conflicts verified).
template<bool OUT_I8>
__device__ __forceinline__ void gemm_core(
    const i8* __restrict__ X, const i8* __restrict__ W, const float* __restrict__ bias,
    void* __restrict__ out, float alpha, int M, int N, int K, i8* lds)
{
    const int nt = K >> 6;
    const int nwg = (M >> 8) * (N >> 7);
    const int q = nwg >> 3;
    const int lin = blockIdx.x;
    const int wg = (lin & 7) * q + (lin >> 3);
    const int nbm = M >> 8;
    const int m0 = (wg % nbm) * 256, n0 = (wg / nbm) * 128;

    const int tid = threadIdx.x, lane = tid & 63, wave = tid >> 6;
    const int wr = wave >> 1, wc = wave & 1, l4 = lane & 15, lh = lane >> 4;

    const int g4 = lh ^ ((l4 >> 1) & 3);
    const int aoff = (wr * 64 + l4) * 64 + g4 * 16;
    const int boff = 16384 + (wc * 64 + l4) * 64 + g4 * 16;

    const int srow = tid >> 2;
    const int sg = (tid & 3) ^ ((tid >> 3) & 3);
    const i8* Asrc = X + (size_t)(m0 + srow) * K + sg * 16;
    const i8* Bsrc = W + (size_t)(n0 + srow) * K + sg * 16;
    const size_t rstep = (size_t)128 * K;
    const int ldst = wave * 1024;

#define BUF3(t_) (lds + ((t_) % 3) * 24576)
#define STAGE3(t_) do { int kb_ = (t_) * 64; i8* lb_ = BUF3(t_);             \
        gload16(Asrc + kb_,         lb_ + ldst);                             \
        gload16(Asrc + rstep + kb_, lb_ + 8192 + ldst);                      \
        gload16(Bsrc + kb_,         lb_ + 16384 + ldst); } while (0)

    int32x4 acc[4][4];
#pragma unroll
    for (int m = 0; m < 4; ++m)
#pragma unroll
        for (int n = 0; n < 4; ++n) acc[m][n] = int32x4{0, 0, 0, 0};

    STAGE3(0);
    STAGE3(1);

    for (int t = 0; t < nt; ++t) {
        const i8* Tb = BUF3(t);
        if (t + 1 < nt) { WAIT_VM3(); } else { WAIT_VM0(); }
        __builtin_amdgcn_s_barrier();
        COMPILER_FENCE();

        if (t + 2 < nt) STAGE3(t + 2);

        int32x4 a0, a1, a2, a3, b0, b1, b2, b3;
        a0 = ld16(Tb + aoff);
        b0 = ld16(Tb + boff);        b1 = ld16(Tb + boff + 1024);
        b2 = ld16(Tb + boff + 2048); b3 = ld16(Tb + boff + 3072);
        a1 = ld16(Tb + aoff + 1024);
        a2 = ld16(Tb + aoff + 2048); a3 = ld16(Tb + aoff + 3072);
        __builtin_amdgcn_s_setprio(1);
        acc[0][0] = MFMA_I8(a0, b0, acc[0][0]);
        acc[0][1] = MFMA_I8(a0, b1, acc[0][1]);
        acc[0][2] = MFMA_I8(a0, b2, acc[0][2]);
        acc[0][3] = MFMA_I8(a0, b3, acc[0][3]);
        acc[1][0] = MFMA_I8(a1, b0, acc[1][0]);
        acc[1][1] = MFMA_I8(a1, b1, acc[1][1]);
        acc[1][2] = MFMA_I8(a1, b2, acc[1][2]);
        acc[1][3] = MFMA_I8(a1, b3, acc[1][3]);
        acc[2][0] = MFMA_I8(a2, b0, acc[2][0]);
        acc[2][1] = MFMA_I8(a2, b1, acc[2][1]);
        acc[2][2] = MFMA_I8(a2, b2, acc[2][2]);
        acc[2][3] = MFMA_I8(a2, b3, acc[2][3]);
        acc[3][0] = MFMA_I8(a3, b0, acc[3][0]);
        acc[3][1] = MFMA_I8(a3, b1, acc[3][1]);
        acc[3][2] = MFMA_I8(a3, b2, acc[3][2]);
        acc[3][3] = MFMA_I8(a3, b3, acc[3][3]);
        __builtin_amdgcn_s_setprio(0);
    }
#undef BUF3
#undef STAGE3

#pragma unroll
    for (int m = 0; m < 4; ++m)
#pragma unroll
        for (int n = 0; n < 4; ++n)
#pragma unroll
            for (int r = 0; r < 4; ++r) {
                int grow = m0 + wr * 64 + m * 16 + lh * 4 + r;
                int gcol = n0 + wc * 64 + n * 16 + l4;
                float y = alpha * (float)acc[m][n][r] + bias[gcol];
                if (OUT_I8) {
                    float v = rintf(y);
                    v = fminf(fmaxf(v, -128.0f), 127.0f);
                    reinterpret_cast<i8*>(out)[(size_t)grow * N + gcol] = (i8)v;
                } else {
                    reinterpret_cast<float*>(out)[(size_t)grow * N + gcol] = y;
                }
            }
}

// fused Q/K/V projection: blockIdx.z selects weight/bias/dst
__global__ __launch_bounds__(512, 4) void k_gemm_qkv(
    const i8* __restrict__ X,
    const i8* __restrict__ w0, const i8* __restrict__ w1, const i8* __restrict__ w2,
    const float* __restrict__ b0, const float* __restrict__ b1, const float* __restrict__ b2,
    i8* __restrict__ o0, i8* __restrict__ o1, i8* __restrict__ o2,
    float alpha, int M, int N, int K)
{
    __shared__ __align__(16) i8 lds[3 * 24576];
    int z = blockIdx.z;
    const i8* W = (z == 0) ? w0 : (z == 1) ? w1 : w2;
    const float* bias = (z == 0) ? b0 : (z == 1) ? b1 : b2;
    i8* out = (z == 0) ? o0 : (z == 1) ? o1 : o2;
    gemm_core<true>(X, W, bias, out, alpha, M, N, K, lds);
}

__global__ __launch_bounds__(512, 4) void k_gemm_out(
    const i8* __restrict__ X, const i8* __restrict__ W, const float* __restrict__ bias,
    float* __restrict__ out, float alpha, int M, int N, int K)
{
    __shared__ __align__(16) i8 lds[3 * 24576];
    gemm_core<false>(X, W, bias, out, alpha, M, N, K, lds);
}

// ---------------- rope, vectorized: (B,S,H,D) -> (B,H,S,D) ----------------
// 16 threads per row, 16B per thread. Rotary pairs (d, d^1) are within the
// thread's own 16B chunk -> no shuffles. Loads fully contiguous (4KB/block);
// stores 256B-contiguous per row. Table reads: 32B/thread, L2-resident.
__global__ void k_rope(const i8* __restrict__ qin, const i8* __restrict__ kin,
                       i8* __restrict__ qout, i8* __restrict__ kout,
                       const float* __restrict__ sin_t, const float* __restrict__ cos_t)
{
    const i8* in = blockIdx.y ? kin : qin;
    i8* outp = blockIdx.y ? kout : qout;
    int t = threadIdx.x;
    int row = blockIdx.x * 16 + (t >> 4);   // (b*S + s)*H + h
    int seg = t & 15;
    int b = row >> 14;                      // / (S*H)
    int s = (row >> 4) & 1023;
    int h = row & 15;
    union { int32x4 v; i8 b8[16]; } u;
    u.v = ld16(in + (size_t)row * D_ + seg * 16);
    if (seg < 4) {                          // d = seg*16 + j < 64
#pragma unroll
        for (int j = 0; j < 16; j += 2) {
            int i = (seg * 16 + j) >> 1;
            float c = cos_t[s * 32 + i], sn = sin_t[s * 32 + i];
            float f1 = (float)u.b8[j], f2 = (float)u.b8[j + 1];
            float r0 = __fadd_rn(__fmul_rn(f1, c), __fmul_rn(-f2, sn));
            float r1 = __fadd_rn(__fmul_rn(f2, c), __fmul_rn(f1, sn));
            u.b8[j]     = (i8)truncf(fminf(fmaxf(r0, -128.0f), 127.0f));
            u.b8[j + 1] = (i8)truncf(fminf(fmaxf(r1, -128.0f), 127.0f));
        }
    }
    *reinterpret_cast<int32x4*>(
        outp + ((size_t)(b * H_ + h) * S_ + s) * D_ + seg * 16) = u.v;
}

// ---------------- V transpose: (B,S,H,D) -> (B,H,D,S) ----------------
__global__ void k_vtrans(const i8* __restrict__ vin, i8* __restrict__ vout) {
    __shared__ int tile[64][17];
    int bh = blockIdx.z;
    int b = bh >> 4, h = bh & 15;
    int s0 = blockIdx.x * 64, d0 = blockIdx.y * 64;
    int t = threadIdx.x;
    {
        int sr = t >> 2, dq = (t & 3) * 16;
        int32x4 v = ld16(vin + ((size_t)(b * S_ + s0 + sr) * H_ + h) * D_ + d0 + dq);
#pragma unroll
        for (int j = 0; j < 4; ++j) tile[sr][dq / 4 + j] = v[j];
    }
    __syncthreads();
    {
        int dr = t >> 2, sq = (t & 3) * 16;
        union { int32x4 v; i8 b[16]; } u;
        const i8* tb = reinterpret_cast<const i8*>(tile);
#pragma unroll
        for (int j = 0; j < 16; ++j) u.b[j] = tb[(sq + j) * 68 + dr];
        *reinterpret_cast<int32x4*>(vout + ((size_t)bh * D_ + d0 + dr) * S_ + s0 + sq) = u.v;
    }
}

// ---------------- fused int8 attention (R8 version) ----------------
struct AttnShared {
    float slx[4][32];
    float r127[32];
    __align__(16) i8 plds[32][80];
};

__device__ __forceinline__ void attn_chunk(int qc, int bh, int tid,
    const i8* __restrict__ Qh, const i8* __restrict__ Kb, const i8* __restrict__ Vb,
    i8* __restrict__ O, AttnShared& sh)
{
    const float C2 = 1.25e-5f * 1.44269504088896f;   // A_QK/16 * log2(e)
    const float APV = 1.0f / 127.0f;
    const int lane = tid & 63, wave = tid >> 6;
    const int l4 = lane & 15, lh = lane >> 4;
    const i8* Qb = Qh + (size_t)(qc * 32) * D_;
    const int nt = (qc * 32 + 31) / 64 + 1;

    int32x4 aq[2][4];
#pragma unroll
    for (int m = 0; m < 2; ++m)
#pragma unroll
        for (int kk = 0; kk < 4; ++kk)
            aq[m][kk] = ld16(Qb + (size_t)(m * 16 + l4) * D_ + kk * 64 + lh * 16);

    float sum_[2][4];
#pragma unroll
    for (int m = 0; m < 2; ++m)
#pragma unroll
        for (int r = 0; r < 4; ++r) sum_[m][r] = 0.0f;

    for (int kt = 0; kt < nt; ++kt) {
        int cb = kt * 64 + wave * 16;
        int32x4 acc0 = int32x4{0,0,0,0}, acc1 = int32x4{0,0,0,0};
#pragma unroll
        for (int kk = 0; kk < 4; ++kk) {
            int32x4 bf = ld16(Kb + (size_t)(cb + l4) * D_ + kk * 64 + lh * 16);
            acc0 = MFMA_I8(aq[0][kk], bf, acc0);
            acc1 = MFMA_I8(aq[1][kk], bf, acc1);
        }
        int gcol = cb + l4;
#pragma unroll
        for (int m = 0; m < 2; ++m) {
            int32x4 accm = m ? acc1 : acc0;
#pragma unroll
            for (int r = 0; r < 4; ++r) {
                int grow = qc * 32 + m * 16 + lh * 4 + r;
                float e = (gcol <= grow) ? exp2f((float)accm[r] * C2) : 0.0f;
                sum_[m][r] += e;
            }
        }
    }

#pragma unroll
    for (int m = 0; m < 2; ++m)
#pragma unroll
        for (int r = 0; r < 4; ++r) {
            float s = sum_[m][r];
            s += __shfl_xor(s, 1);
            s += __shfl_xor(s, 2);
            s += __shfl_xor(s, 4);
            s += __shfl_xor(s, 8);
            if (l4 == 0) sh.slx[wave][m * 16 + lh * 4 + r] = s;
        }
    __syncthreads();
    if (tid < 32)
        sh.r127[tid] = 127.0f /
            (sh.slx[0][tid] + sh.slx[1][tid] + sh.slx[2][tid] + sh.slx[3][tid]);
    __syncthreads();

    int32x4 oacc[2][4];
#pragma unroll
    for (int m = 0; m < 2; ++m)
#pragma unroll
        for (int n = 0; n < 4; ++n) oacc[m][n] = int32x4{0, 0, 0, 0};

    for (int kt = 0; kt < nt; ++kt) {
        int cb = kt * 64 + wave * 16;
        int32x4 acc0 = int32x4{0,0,0,0}, acc1 = int32x4{0,0,0,0};
#pragma unroll
        for (int kk = 0; kk < 4; ++kk) {
            int32x4 bf = ld16(Kb + (size_t)(cb + l4) * D_ + kk * 64 + lh * 16);
            acc0 = MFMA_I8(aq[0][kk], bf, acc0);
            acc1 = MFMA_I8(aq[1][kk], bf, acc1);
        }
        int gcol = cb + l4;
        i8 pv[2][4];
#pragma unroll
        for (int m = 0; m < 2; ++m) {
            int32x4 accm = m ? acc1 : acc0;
#pragma unroll
            for (int r = 0; r < 4; ++r) {
                int rowi = m * 16 + lh * 4 + r;
                int grow = qc * 32 + rowi;
                float e = (gcol <= grow) ? exp2f((float)accm[r] * C2) : 0.0f;
                pv[m][r] = (i8)(int)rintf(e * sh.r127[rowi]);
            }
        }
        __syncthreads();
#pragma unroll
        for (int m = 0; m < 2; ++m)
#pragma unroll
            for (int r = 0; r < 4; ++r)
                sh.plds[m * 16 + lh * 4 + r][wave * 16 + l4] = pv[m][r];
        __syncthreads();
        int32x4 a0 = ld16(&sh.plds[l4][lh * 16]);
        int32x4 a1 = ld16(&sh.plds[16 + l4][lh * 16]);
#pragma unroll
        for (int n = 0; n < 4; ++n) {
            int32x4 bf = ld16(Vb + (size_t)(wave * 64 + n * 16 + l4) * S_ + kt * 64 + lh * 16);
            oacc[0][n] = MFMA_I8(a0, bf, oacc[0][n]);
            oacc[1][n] = MFMA_I8(a1, bf, oacc[1][n]);
        }
    }

    int b = bh >> 4, h = bh & 15;
#pragma unroll
    for (int m = 0; m < 2; ++m)
#pragma unroll
        for (int r = 0; r < 4; ++r) {
            int s = qc * 32 + m * 16 + lh * 4 + r;
#pragma unroll
            for (int n = 0; n < 4; ++n) {
                float o = rintf(APV * (float)oacc[m][n][r]);
                o = fminf(fmaxf(o, -128.0f), 127.0f);
                O[((size_t)(b * S_ + s) * H_ + h) * D_ + wave * 64 + n * 16 + l4] = (i8)o;
            }
        }
}

// Pair chunks (p, 31-p): every block does ~17 k-tiles -> uniform runtime.
__global__ __launch_bounds__(256) void k_attn(const i8* __restrict__ Q, const i8* __restrict__ K,
                                              const i8* __restrict__ V, i8* __restrict__ O)
{
    __shared__ AttnShared sh;
    int bh = blockIdx.x;
    int p = blockIdx.y;
    int tid = threadIdx.x;
    const i8* Qh = Q + (size_t)bh * S_ * D_;
    const i8* Kb = K + (size_t)bh * S_ * D_;
    const i8* Vb = V + (size_t)bh * D_ * S_;
    attn_chunk((S_ / 32 - 1) - p, bh, tid, Qh, Kb, Vb, O, sh);
    attn_chunk(p, bh, tid, Qh, Kb, Vb, O, sh);
}

extern "C" void kernel_launch(void* const* d_in, const int* in_sizes, int n_in,
                              void* d_out, int out_size, void* d_ws, size_t ws_size,
                              hipStream_t stream) {
    const float* hs = (const float*)d_in[0];
    const float* Wq = (const float*)d_in[1];
    const float* Wk = (const float*)d_in[2];
    const float* Wv = (const float*)d_in[3];
    const float* Wo = (const float*)d_in[4];
    const float* bq = (const float*)d_in[5];
    const float* bk = (const float*)d_in[6];
    const float* bv = (const float*)d_in[7];
    const float* bo = (const float*)d_in[8];
    float* out = (float*)d_out;

    size_t off = 0;
    char* wsb = (char*)d_ws;
    auto carve = [&](size_t bytes) { char* p = wsb + off; off += (bytes + 255) & ~(size_t)255; return p; };
    const size_t ME = (size_t)B_ * S_ * E_;   // 8.4 MB
    const size_t EE = (size_t)E_ * E_;        // 16.8 MB
    i8* x8  = (i8*)carve(ME);
    i8* wq8 = (i8*)carve(EE);
    i8* wk8 = (i8*)carve(EE);
    i8* wv8 = (i8*)carve(EE);
    i8* wo8 = (i8*)carve(EE);
    i8* q8  = (i8*)carve(ME);
    i8* k8  = (i8*)carve(ME);
    i8* v8  = (i8*)carve(ME);
    i8* qr  = (i8*)carve(ME);
    i8* kr  = (i8*)carve(ME);
    i8* vt  = (i8*)carve(ME);
    i8* o8  = (i8*)carve(ME);
    float* sin_t = (float*)carve((size_t)S_ * 32 * 4);
    float* cos_t = (float*)carve((size_t)S_ * 32 * 4);

    int n4_me = (int)(ME / 4), n4_ee = (int)(EE / 4);
    k_f32_to_i8<<<(n4_me + 255) / 256, 256, 0, stream>>>(hs, x8, n4_me);
    k_w_to_i8<<<dim3((n4_ee + 255) / 256, 4), 256, 0, stream>>>(
        Wq, Wk, Wv, Wo, wq8, wk8, wv8, wo8, n4_ee);
    k_sincos<<<(S_ * 32 + 255) / 256, 256, 0, stream>>>(sin_t, cos_t);

    const int M = B_ * S_, N = E_, Kd = E_;
    const int nwg = (M / 256) * (N / 128);   // 256 blocks per z
    k_gemm_qkv<<<dim3(nwg, 1, 3), 512, 0, stream>>>(
        x8, wq8, wk8, wv8, bq, bk, bv, q8, k8, v8, 0.00012f, M, N, Kd);

    k_rope<<<dim3((B_ * S_ * H_) / 16, 2), 256, 0, stream>>>(q8, k8, qr, kr, sin_t, cos_t);
    k_vtrans<<<dim3(S_ / 64, D_ / 64, B_ * H_), 256, 0, stream>>>(v8, vt);
    k_attn<<<dim3(B_ * H_, S_ / 64), 256, 0, stream>>>(qr, kr, vt, o8);

    k_gemm_out<<<nwg, 512, 0, stream>>>(o8, wo8, bo, out, 0.01f, M, N, Kd);
}